// Round 10
// baseline (524.081 us; speedup 1.0000x reference)
//
#include <hip/hip_runtime.h>
#include <hip/hip_bf16.h>

// Two-phase FeedForward_denoise:
//   K1 (r10): MFMA split-bf16 GEMM, 4 pixel-tiles/block, LDS double buffer.
//       Register restructure: acc[ci][pj] only accumulates within one pj
//       iteration -> per-pj local acc (64->16 VGPRs) with immediate stores
//       (overlap next pj's MFMAs). launch_bounds(256,3): peak regs ~140 so
//       the 168 cap is safe (r7's spill mode was a 85-cap on ~190 live).
//       Bit-identical math to r6 K1 (loop reorder only).
//   K2 (r6 verbatim, best measured 289 us): u16 LDS halo, 2x2-patch B
//       phases, halo prefetch, 32-col gate ring s_g, MFMA project_out at
//       chunks 7/15. (r9's 16-col ring raised VGPR to 108 -> no occupancy
//       gain + extra barriers = 302 us; reverted.)
// Fallback to the fully-fused kernel if ws_size < 201 MB.

#define T 16
#define R20 20
#define R18 18
#define HW 65536
#define XC_BYTES ((size_t)4 * 16 * HW * 24 * 2)

typedef unsigned short u16;
typedef unsigned int u32;

typedef __attribute__((ext_vector_type(8))) short bf16x8;
typedef __attribute__((ext_vector_type(4))) float f32x4;
typedef __attribute__((ext_vector_type(2))) float f32x2;

__device__ __forceinline__ float bflo(u32 w) {
    union { u32 i; float f; } v; v.i = w << 16; return v.f;
}
__device__ __forceinline__ float bfhi(u32 w) {
    union { u32 i; float f; } v; v.i = w & 0xffff0000u; return v.f;
}
__device__ __forceinline__ float bf2f(u16 u) {
    union { u32 i; float f; } v; v.i = ((u32)u) << 16; return v.f;
}
__device__ __forceinline__ u16 f2bf(float f) {
    union { float f; u32 i; } v; v.f = f;
    u32 x = v.i;
    u32 r = (x + 0x7fffu + ((x >> 16) & 1u)) >> 16;
    return (u16)r;
}
__device__ __forceinline__ u32 f2bf2(float a, float b) {
    return (u32)f2bf(a) | ((u32)f2bf(b) << 16);
}
__device__ __forceinline__ float gelu_exact(float v) {
    return 0.5f * v * (1.0f + erff(v * 0.70710678118654752f));
}
// Branch-free erf, A&S 7.1.26 (|err| ~1e-6) — inputs bf16-rounded already.
__device__ __forceinline__ float erf_fast(float x) {
    float ax = fabsf(x);
    float t = __builtin_amdgcn_rcpf(fmaf(0.3275911f, ax, 1.0f));
    float p = fmaf(t, 1.061405429f, -1.453152027f);
    p = fmaf(t, p, 1.421413741f);
    p = fmaf(t, p, -0.284496736f);
    p = fmaf(t, p, 0.254829592f);
    p = p * t;
    float e = __expf(-ax * ax);
    float r = fmaf(-p, e, 1.0f);
    return copysignf(r, x);
}
__device__ __forceinline__ float gelu_fast(float v) {
    return 0.5f * v * (1.0f + erf_fast(v * 0.70710678118654752f));
}

// Exact split of two fp32 into packed-bf16 hi (truncated) and lo (residual).
__device__ __forceinline__ void pack_pair(float a, float b, u32& hi, u32& lo) {
    union { float f; u32 i; } ua, ub, ha, hb, la, lb;
    ua.f = a; ub.f = b;
    ha.i = ua.i & 0xffff0000u;
    hb.i = ub.i & 0xffff0000u;
    hi = (ha.i >> 16) | hb.i;
    la.f = a - ha.f;
    lb.f = b - hb.f;
    lo = (la.i >> 16) | (lb.i & 0xffff0000u);
}

// ---------------------------------------------------------------------------
// K1: MFMA split-bf16 GEMM, 4 tiles/block, LDS dbuf, per-pj acc + immediate
// stores (low register pressure), direct scattered 8B stores.
// ---------------------------------------------------------------------------
__global__ __launch_bounds__(256, 3)
void k1_proj_mfma(const float* __restrict__ xin,   // [4][64][256][256]
                  const float* __restrict__ pnin,  // [4][2][256][256]
                  const float* __restrict__ w_in,  // [256][64]
                  const float* __restrict__ b_in,  // [256]
                  const float* __restrict__ w_pn,  // [128][2]
                  const float* __restrict__ b_pn,  // [128]
                  u16* __restrict__ xc)            // [4][16][HW][24] bf16
{
    __shared__ float s_x[2][64][65];               // 2 x 16.6 KB
    __shared__ float s_bin[256];

    const int tid  = threadIdx.x;
    const int b    = blockIdx.y;
    const int pxbase = blockIdx.x * 256;           // 4 tiles of 64 px
    const int lane = tid & 63;
    const int wid  = tid >> 6;
    const int lr   = lane & 15;        // MFMA row/col-in-16 index
    const int lh   = lane >> 4;        // MFMA k-group index
    const int CB   = wid * 64;         // this wave's channel base
    const int wu   = __builtin_amdgcn_readfirstlane(wid);

    s_bin[tid] = b_in[tid];

    // ---- w fragments: hi/lo bf16, loaded once per block -------------------
    bf16x8 whi[4][2], wlo[4][2];
#pragma unroll
    for (int ci = 0; ci < 4; ++ci)
#pragma unroll
        for (int ks = 0; ks < 2; ++ks) {
            const float* wp = w_in + (size_t)(CB + 16 * ci + lr) * 64
                            + 32 * ks + 8 * lh;
            float4 A0 = *(const float4*)wp;
            float4 A1 = *(const float4*)(wp + 4);
            union { u32 u[4]; bf16x8 v; } H, L;
            pack_pair(A0.x, A0.y, H.u[0], L.u[0]);
            pack_pair(A0.z, A0.w, H.u[1], L.u[1]);
            pack_pair(A1.x, A1.y, H.u[2], L.u[2]);
            pack_pair(A1.z, A1.w, H.u[3], L.u[3]);
            whi[ci][ks] = H.v; wlo[ci][ks] = L.v;
        }

    // ---- prologue: stage tile 0 -------------------------------------------
    {
        const float* xb = xin + (size_t)b * 64 * HW + pxbase;
#pragma unroll
        for (int i = 0; i < 4; ++i) {
            int idx = tid + 256 * i;
            int row = idx >> 4, seg = (idx & 15) * 4;
            float4 v = *(const float4*)(xb + (size_t)row * HW + seg);
            s_x[0][row][seg + 0] = v.x; s_x[0][row][seg + 1] = v.y;
            s_x[0][row][seg + 2] = v.z; s_x[0][row][seg + 3] = v.w;
        }
    }

    int cur = 0;
#pragma unroll 1
    for (int t = 0; t < 4; ++t) {
        const int px0 = pxbase + t * 64;

        // issue next-tile global loads (land after this tile's compute)
        float4 nx[4];
        if (t < 3) {
            const float* xb = xin + (size_t)b * 64 * HW + px0 + 64;
#pragma unroll
            for (int i = 0; i < 4; ++i) {
                int idx = tid + 256 * i;
                int row = idx >> 4, seg = (idx & 15) * 4;
                nx[i] = *(const float4*)(xb + (size_t)row * HW + seg);
            }
        }
        float p0 = pnin[(size_t)b * 2 * HW + px0 + lane];
        float p1 = pnin[(size_t)b * 2 * HW + HW + px0 + lane];

        __syncthreads();   // s_x[cur] fully staged (prologue or prev tail)

        // ---- pn projection: direct 8B stores ------------------------------
#pragma unroll
        for (int q = 0; q < 8; ++q) {
            int k = 32 * wu + 4 * q;           // wave-uniform quad base, <128
            int c = k / 12, l = k - 12 * c;    // l in {0,4,8}
            float v0 = fmaf(w_pn[2*k+0], p0, fmaf(w_pn[2*k+1], p1, b_pn[k+0]));
            float v1 = fmaf(w_pn[2*k+2], p0, fmaf(w_pn[2*k+3], p1, b_pn[k+1]));
            float v2 = fmaf(w_pn[2*k+4], p0, fmaf(w_pn[2*k+5], p1, b_pn[k+2]));
            float v3 = fmaf(w_pn[2*k+6], p0, fmaf(w_pn[2*k+7], p1, b_pn[k+3]));
            uint2 val;
            val.x = f2bf2(v0, v1);
            val.y = f2bf2(v2, v3);
            *(uint2*)(xc + ((size_t)(b * 16 + c) * HW + px0 + lane) * 24 + l) = val;
        }

        // ---- MFMA: per pj, compute 4 ci accumulators and store immediately -
#pragma unroll
        for (int pj = 0; pj < 4; ++pj) {
            bf16x8 xh[2], xl[2];
#pragma unroll
            for (int ks = 0; ks < 2; ++ks) {
                const int rb = 32 * ks + 8 * lh;
                const int cb = 16 * pj + lr;
                float x0 = s_x[cur][rb + 0][cb], x1 = s_x[cur][rb + 1][cb];
                float x2 = s_x[cur][rb + 2][cb], x3 = s_x[cur][rb + 3][cb];
                float x4 = s_x[cur][rb + 4][cb], x5 = s_x[cur][rb + 5][cb];
                float x6 = s_x[cur][rb + 6][cb], x7 = s_x[cur][rb + 7][cb];
                union { u32 u[4]; bf16x8 v; } H, L;
                pack_pair(x0, x1, H.u[0], L.u[0]);
                pack_pair(x2, x3, H.u[1], L.u[1]);
                pack_pair(x4, x5, H.u[2], L.u[2]);
                pack_pair(x6, x7, H.u[3], L.u[3]);
                xh[ks] = H.v; xl[ks] = L.v;
            }
#pragma unroll
            for (int ci = 0; ci < 4; ++ci) {
                f32x4 a = (f32x4){0.f, 0.f, 0.f, 0.f};
#pragma unroll
                for (int ks = 0; ks < 2; ++ks) {
                    a = __builtin_amdgcn_mfma_f32_16x16x32_bf16(
                        whi[ci][ks], xh[ks], a, 0, 0, 0);
                    a = __builtin_amdgcn_mfma_f32_16x16x32_bf16(
                        whi[ci][ks], xl[ks], a, 0, 0, 0);
                    a = __builtin_amdgcn_mfma_f32_16x16x32_bf16(
                        wlo[ci][ks], xh[ks], a, 0, 0, 0);
                }
                // bias + bf16 + direct store (same mapping as r6)
                const int kk = CB + 16 * ci + 4 * lh;
                float b0 = s_bin[kk + 0], b1 = s_bin[kk + 1];
                float b2 = s_bin[kk + 2], b3 = s_bin[kk + 3];
                int c, l;
                int kg = kk + 128;
                if (kg < 192) { c = kg / 12; l = kg - 12 * c; }
                else { int t2 = kg - 192; int cq = t2 / 12; c = cq; l = 12 + (t2 - 12 * cq); }
                u16* rec = xc + ((size_t)(b * 16 + c) * HW + px0) * 24 + l;
                uint2 val;
                val.x = f2bf2(a[0] + b0, a[1] + b1);
                val.y = f2bf2(a[2] + b2, a[3] + b3);
                *(uint2*)(rec + (size_t)(16 * pj + lr) * 24) = val;
            }
        }

        // ---- tail: write prefetched tile into other buffer ----------------
        // Safe: all threads passed this iteration's barrier, so no thread is
        // still reading s_x[cur^1] (consumed in iteration t-1).
        if (t < 3) {
#pragma unroll
            for (int i = 0; i < 4; ++i) {
                int idx = tid + 256 * i;
                int row = idx >> 4, seg = (idx & 15) * 4;
                float* d = &s_x[cur ^ 1][row][seg];
                d[0] = nx[i].x; d[1] = nx[i].y; d[2] = nx[i].z; d[3] = nx[i].w;
            }
            cur ^= 1;
        }
    }
}

// ---------------------------------------------------------------------------
// K2: spatial convs + gating; project_out via MFMA gate passes. (r6 verbatim)
// ---------------------------------------------------------------------------
__global__ __launch_bounds__(512, 2)
void k2_spatial(const u16* __restrict__ xc,       // [4][16][HW][24] bf16
                const float* __restrict__ w_dw1,  const float* __restrict__ b_dw1,
                const float* __restrict__ w_dw3a, const float* __restrict__ b_dw3a,
                const float* __restrict__ w_dw3b, const float* __restrict__ b_dw3b,
                const float* __restrict__ w_out,  const float* __restrict__ b_out,
                float* __restrict__ outp)         // [4][64][256][256]
{
    __shared__ __align__(8) u16 s_xc[24][R20 * R20];
    __shared__ __align__(8) u16 s_d3a[8][R18 * R18];
    __shared__ __align__(8) u16 s_d1[8][T * T];
    __shared__ __align__(8) u16 s_d3[8][T * T];
    __shared__ __align__(16) u16 s_g[2][256][40];  // [half][px][gate-col ring]
    __shared__ float s_wd1[8][27];
    __shared__ float s_wd3a[8][27];
    __shared__ float s_wd3b[8][9];
    __shared__ float s_b1[8], s_b3a[8], s_b3b[8];

    const int tid  = threadIdx.x;
    const int half = tid >> 8;          // wave-uniform (waves 0-3 vs 4-7)
    const int pix  = tid & 255;
    const int ox0 = blockIdx.x * T;
    const int oy0 = blockIdx.y * T;
    const int b   = blockIdx.z;

    // MFMA pass role: wave w -> gh (which gate half), cw (ch-tile),
    // ph (px-half). Out rows [32gh+16cw, +16), px-tiles 8ph..8ph+7.
    const int w    = tid >> 6;
    const int lane = tid & 63;
    const int lr   = lane & 15;
    const int lh   = lane >> 4;
    const int gh   = w >> 2;
    const int cw   = (w >> 1) & 1;
    const int ph   = w & 1;

    // ---- halo prefetch state (chunk-invariant coords) ---------------------
    int hpy = tid / R20, hpx = tid - hpy * R20;     // meaningful for tid<400
    int hgy = oy0 - 2 + hpy, hgx = ox0 - 2 + hpx;
    const bool pvalid = (tid < 400) &&
                        ((unsigned)hgy < 256u) && ((unsigned)hgx < 256u);
    const u16* psrc = xc + ((size_t)(b * 16) * HW
                            + (pvalid ? (hgy * 256 + hgx) : 0)) * 24;
    uint4 pv0, pv1, pv2;
    pv0 = pv1 = pv2 = make_uint4(0, 0, 0, 0);
    if (pvalid) {
        const uint4* s = (const uint4*)psrc;
        pv0 = s[0]; pv1 = s[1]; pv2 = s[2];
    }

    f32x4 acc[8];      // 8 px-tiles of this wave's 16-ch out slice
#pragma unroll
    for (int t = 0; t < 8; ++t) acc[t] = (f32x4){0.f, 0.f, 0.f, 0.f};

    for (int chunk = 0; chunk < 16; ++chunk) {
        const int c0 = chunk * 4;
        __syncthreads();   // protect s_* reuse across chunks

        // ---- Phase W: stage chunk weights into LDS -------------------------
        {
            int t = tid;
            if (t < 216) {
                int gl = t / 27, idx = t - gl * 27;
                int g = (gl < 4) ? (c0 + gl) : (c0 + 60 + gl);
                s_wd1[gl][idx] = w_dw1[g * 27 + idx];
            } else if (t < 432) {
                int t2 = t - 216;
                int gl = t2 / 27, idx = t2 - gl * 27;
                int g = (gl < 4) ? (c0 + gl) : (c0 + 60 + gl);
                s_wd3a[gl][idx] = w_dw3a[g * 27 + idx];
            } else if (t < 504) {
                int t2 = t - 432;
                int gl = t2 / 9, idx = t2 - gl * 9;
                int g = (gl < 4) ? (c0 + gl) : (c0 + 60 + gl);
                s_wd3b[gl][idx] = w_dw3b[g * 9 + idx];
            } else if (t < 512) {
                int gl = t - 504;
                int g = (gl < 4) ? (c0 + gl) : (c0 + 60 + gl);
                s_b1[gl]  = b_dw1[g];
                s_b3a[gl] = b_dw3a[g];
                s_b3b[gl] = b_dw3b[g];
            }
        }

        // ---- Phase A: write prefetched halo, then issue chunk+1 loads ------
        if (tid < 400) {
            union { uint4 q[3]; u16 h[24]; } v;
            v.q[0] = pv0; v.q[1] = pv1; v.q[2] = pv2;
#pragma unroll
            for (int l = 0; l < 24; ++l) s_xc[l][tid] = v.h[l];
        }
        {
            uint4 n0, n1, n2;
            n0 = n1 = n2 = make_uint4(0, 0, 0, 0);
            if (pvalid && chunk < 15) {
                const uint4* s = (const uint4*)(psrc
                                 + (size_t)(chunk + 1) * HW * 24);
                n0 = s[0]; n1 = s[1]; n2 = s[2];
            }
            pv0 = n0; pv1 = n1; pv2 = n2;   // waitcnt lands at next-iter use
        }
        __syncthreads();

        // ---- Phase B1a: d3a (grouped 3x3) over 18x18, 2x2 per thread -------
        for (int task = tid; task < 8 * 81; task += 512) {
            int gl = task / 81, patch = task - gl * 81;
            int py = (patch / 9) * 2, px = (patch - (patch / 9) * 9) * 2;
            float bias = s_b3a[gl];
            float a00 = bias, a01 = bias, a10 = bias, a11 = bias;
#pragma unroll
            for (int j = 0; j < 3; ++j) {
                int lc = (gl < 4) ? (3 * gl + j) : (12 + 3 * (gl - 4) + j);
                const u32* base = (const u32*)&s_xc[lc][0];
                float win[4][4];
#pragma unroll
                for (int r = 0; r < 4; ++r) {
                    int e = (py + r) * R20 + px;   // even
                    u32 u0 = base[e >> 1];
                    u32 u1 = base[(e >> 1) + 1];
                    win[r][0] = bflo(u0); win[r][1] = bfhi(u0);
                    win[r][2] = bflo(u1); win[r][3] = bfhi(u1);
                }
#pragma unroll
                for (int ky = 0; ky < 3; ++ky)
#pragma unroll
                    for (int kx = 0; kx < 3; ++kx) {
                        float wgt = s_wd3a[gl][j * 9 + ky * 3 + kx];
                        a00 = fmaf(wgt, win[ky][kx], a00);
                        a01 = fmaf(wgt, win[ky][kx + 1], a01);
                        a10 = fmaf(wgt, win[ky + 1][kx], a10);
                        a11 = fmaf(wgt, win[ky + 1][kx + 1], a11);
                    }
            }
            int gy0 = oy0 - 1 + py, gx0 = ox0 - 1 + px;
            bool vy0 = (unsigned)gy0 < 256u, vy1 = (unsigned)(gy0 + 1) < 256u;
            bool vx0 = (unsigned)gx0 < 256u, vx1 = (unsigned)(gx0 + 1) < 256u;
            u16* drow = &s_d3a[gl][py * R18 + px];
            drow[0]       = (vy0 && vx0) ? f2bf(a00) : (u16)0;
            drow[1]       = (vy0 && vx1) ? f2bf(a01) : (u16)0;
            drow[R18]     = (vy1 && vx0) ? f2bf(a10) : (u16)0;
            drow[R18 + 1] = (vy1 && vx1) ? f2bf(a11) : (u16)0;
        }

        // ---- Phase B1b: d1 (grouped 3x3), one 2x2 task per thread ----------
        {
            int gl = tid >> 6, patch = tid & 63;
            int py = (patch >> 3) * 2, px = (patch & 7) * 2;
            float bias = s_b1[gl];
            float a00 = bias, a01 = bias, a10 = bias, a11 = bias;
#pragma unroll
            for (int j = 0; j < 3; ++j) {
                int lc = (gl < 4) ? (3 * gl + j) : (12 + 3 * (gl - 4) + j);
                const u32* base = (const u32*)&s_xc[lc][0];
                float win[4][4];
#pragma unroll
                for (int r = 0; r < 4; ++r) {
                    int e = (py + 1 + r) * R20 + px;   // even; cols px+1..px+4
                    u32 u0 = base[e >> 1];
                    u32 u1 = base[(e >> 1) + 1];
                    u32 u2 = base[(e >> 1) + 2];
                    win[r][0] = bfhi(u0); win[r][1] = bflo(u1);
                    win[r][2] = bfhi(u1); win[r][3] = bflo(u2);
                }
#pragma unroll
                for (int ky = 0; ky < 3; ++ky)
#pragma unroll
                    for (int kx = 0; kx < 3; ++kx) {
                        float wgt = s_wd1[gl][j * 9 + ky * 3 + kx];
                        a00 = fmaf(wgt, win[ky][kx], a00);
                        a01 = fmaf(wgt, win[ky][kx + 1], a01);
                        a10 = fmaf(wgt, win[ky + 1][kx], a10);
                        a11 = fmaf(wgt, win[ky + 1][kx + 1], a11);
                    }
            }
            u16* drow = &s_d1[gl][py * T + px];
            drow[0] = f2bf(a00); drow[1] = f2bf(a01);
            drow[T] = f2bf(a10); drow[T + 1] = f2bf(a11);
        }
        __syncthreads();

        // ---- Phase B2: d3 = depthwise 3x3 over d3a, one task per thread ----
        {
            int gl = tid >> 6, patch = tid & 63;
            int py = (patch >> 3) * 2, px = (patch & 7) * 2;
            float bias = s_b3b[gl];
            float a00 = bias, a01 = bias, a10 = bias, a11 = bias;
            float win[4][4];
            const u32* base = (const u32*)&s_d3a[gl][0];
#pragma unroll
            for (int r = 0; r < 4; ++r) {
                int e = (py + r) * R18 + px;   // even
                u32 u0 = base[e >> 1];
                u32 u1 = base[(e >> 1) + 1];
                win[r][0] = bflo(u0); win[r][1] = bfhi(u0);
                win[r][2] = bflo(u1); win[r][3] = bfhi(u1);
            }
#pragma unroll
            for (int ky = 0; ky < 3; ++ky)
#pragma unroll
                for (int kx = 0; kx < 3; ++kx) {
                    float wgt = s_wd3b[gl][ky * 3 + kx];
                    a00 = fmaf(wgt, win[ky][kx], a00);
                    a01 = fmaf(wgt, win[ky][kx + 1], a01);
                    a10 = fmaf(wgt, win[ky + 1][kx], a10);
                    a11 = fmaf(wgt, win[ky + 1][kx + 1], a11);
                }
            u16* drow = &s_d3[gl][py * T + px];
            drow[0] = f2bf(a00); drow[1] = f2bf(a01);
            drow[T] = f2bf(a10); drow[T + 1] = f2bf(a11);
        }
        __syncthreads();

        // ---- Phase G: gate products -> s_g (bf16), one 8B write -----------
        {
            const u16* sD = (half == 0) ? &s_d1[0][0] : &s_d3[0][0];
            float ga = gelu_fast(bf2f(sD[0 * 256 + pix])) * bf2f(sD[4 * 256 + pix]);
            float gb = gelu_fast(bf2f(sD[1 * 256 + pix])) * bf2f(sD[5 * 256 + pix]);
            float gc = gelu_fast(bf2f(sD[2 * 256 + pix])) * bf2f(sD[6 * 256 + pix]);
            float gd = gelu_fast(bf2f(sD[3 * 256 + pix])) * bf2f(sD[7 * 256 + pix]);
            uint2 val;
            val.x = f2bf2(ga, gb);
            val.y = f2bf2(gc, gd);
            *(uint2*)&s_g[half][pix][c0 & 31] = val;
        }

        // ---- MFMA pass after chunks 7 and 15 (gate cols 0..31 / 32..63) ---
        if (chunk == 7 || chunk == 15) {
            __syncthreads();   // s_g complete for this 32-col window
            const int p = chunk >> 3;
            // A-frag: w_out rows [32gh+16cw+lr], cols 32p+8lh .. +7 (split)
            const float* wp = w_out + (size_t)(32 * gh + 16 * cw + lr) * 64
                            + 32 * p + 8 * lh;
            float4 A0 = *(const float4*)wp;
            float4 A1 = *(const float4*)(wp + 4);
            union { u32 u[4]; bf16x8 v; } H, L;
            pack_pair(A0.x, A0.y, H.u[0], L.u[0]);
            pack_pair(A0.z, A0.w, H.u[1], L.u[1]);
            pack_pair(A1.x, A1.y, H.u[2], L.u[2]);
            pack_pair(A1.z, A1.w, H.u[3], L.u[3]);
            bf16x8 Ah = H.v, Al = L.v;
#pragma unroll
            for (int t = 0; t < 8; ++t) {
                int pt = 8 * ph + t;
                bf16x8 Bv = *(const bf16x8*)&s_g[gh][16 * pt + lr][8 * lh];
                acc[t] = __builtin_amdgcn_mfma_f32_16x16x32_bf16(Ah, Bv, acc[t], 0, 0, 0);
                acc[t] = __builtin_amdgcn_mfma_f32_16x16x32_bf16(Al, Bv, acc[t], 0, 0, 0);
            }
        }
    }

    // ---- Epilogue: bias + fp32 store --------------------------------------
    // D-frag: value r of px-tile t is out[o = 32gh+16cw+4lh+r][px = 16pt+lr]
    {
        const int o = 32 * gh + 16 * cw + 4 * lh;
        float b0 = b_out[o + 0], b1 = b_out[o + 1];
        float b2 = b_out[o + 2], b3 = b_out[o + 3];
#pragma unroll
        for (int t = 0; t < 8; ++t) {
            int pt = 8 * ph + t;
            size_t base = (size_t)b * 64 * HW + (size_t)o * HW
                        + (size_t)(oy0 + pt) * 256 + (ox0 + lr);
            outp[base + 0 * HW] = acc[t][0] + b0;
            outp[base + 1 * HW] = acc[t][1] + b1;
            outp[base + 2 * HW] = acc[t][2] + b2;
            outp[base + 3 * HW] = acc[t][3] + b3;
        }
    }
}

// ---------------------------------------------------------------------------
// Fallback: fully-fused kernel (used only if ws_size < 201 MB).
// ---------------------------------------------------------------------------
__global__ __launch_bounds__(256, 2)
void ffd_fused(const float* __restrict__ xin, const float* __restrict__ pnin,
               const float* __restrict__ w_in, const float* __restrict__ b_in,
               const float* __restrict__ w_pn, const float* __restrict__ b_pn,
               const float* __restrict__ w_dw1, const float* __restrict__ b_dw1,
               const float* __restrict__ w_dw3a, const float* __restrict__ b_dw3a,
               const float* __restrict__ w_dw3b, const float* __restrict__ b_dw3b,
               const float* __restrict__ w_out, const float* __restrict__ b_out,
               float* __restrict__ outp)
{
    __shared__ __align__(8) u16 s_xc[24][R20 * R20];
    __shared__ __align__(8) float s_d3a[8][R18 * R18];
    __shared__ float s_d1[8][T * T];
    __shared__ float s_d3[8][T * T];
    __shared__ float s_wd1[8][27];
    __shared__ float s_wd3a[8][27];
    __shared__ float s_wd3b[8][9];
    __shared__ float s_b1[8], s_b3a[8], s_b3b[8];

    const int tid = threadIdx.x;
    const int ox0 = blockIdx.x * T;
    const int oy0 = blockIdx.y * T;
    const int b   = blockIdx.z;

    float accL[32], accH[32];
#pragma unroll
    for (int o = 0; o < 32; ++o) { accL[o] = 0.f; accH[o] = 0.f; }

    for (int chunk = 0; chunk < 16; ++chunk) {
        const int c0 = chunk * 4;
        __syncthreads();

        for (int t = tid; t < 512; t += 256) {
            if (t < 216) {
                int gl = t / 27, idx = t - gl * 27;
                int g = (gl < 4) ? (c0 + gl) : (c0 + 60 + gl);
                s_wd1[gl][idx] = w_dw1[g * 27 + idx];
            } else if (t < 432) {
                int t2 = t - 216;
                int gl = t2 / 27, idx = t2 - gl * 27;
                int g = (gl < 4) ? (c0 + gl) : (c0 + 60 + gl);
                s_wd3a[gl][idx] = w_dw3a[g * 27 + idx];
            } else if (t < 504) {
                int t2 = t - 432;
                int gl = t2 / 9, idx = t2 - gl * 9;
                int g = (gl < 4) ? (c0 + gl) : (c0 + 60 + gl);
                s_wd3b[gl][idx] = w_dw3b[g * 9 + idx];
            } else {
                int gl = t - 504;
                int g = (gl < 4) ? (c0 + gl) : (c0 + 60 + gl);
                s_b1[gl]  = b_dw1[g];
                s_b3a[gl] = b_dw3a[g];
                s_b3b[gl] = b_dw3b[g];
            }
        }

        for (int p = tid; p < R20 * R20; p += 256) {
            int py = p / R20, px = p - py * R20;
            int gy = oy0 - 2 + py, gx = ox0 - 2 + px;
            if ((unsigned)gy >= 256u || (unsigned)gx >= 256u) {
#pragma unroll 1
                for (int l = 0; l < 24; ++l) s_xc[l][p] = 0;
                continue;
            }
            const int off = gy * 256 + gx;
            float xr[64];
            const float* xp = xin + (size_t)b * 64 * HW + off;
#pragma unroll
            for (int c = 0; c < 64; ++c) xr[c] = xp[(size_t)c * HW];
            float p0 = 0.f, p1 = 0.f;
            if (3 * c0 < 128) {
                const float* pp = pnin + (size_t)b * 2 * HW + off;
                p0 = pp[0]; p1 = pp[HW];
            }
#pragma unroll 1
            for (int l = 0; l < 24; ++l) {
                int k = (l < 12) ? (3 * c0 + l) : (3 * c0 + 192 + (l - 12));
                float acc;
                if (k < 128) {
                    acc = b_pn[k] + w_pn[2 * k] * p0 + w_pn[2 * k + 1] * p1;
                } else {
                    int kk = k - 128;
                    acc = b_in[kk];
                    const float2* wr = (const float2*)(w_in + kk * 64);
#pragma unroll
                    for (int i = 0; i < 32; ++i) {
                        float2 w2 = wr[i];
                        acc = fmaf(w2.x, xr[2 * i], acc);
                        acc = fmaf(w2.y, xr[2 * i + 1], acc);
                    }
                }
                s_xc[l][p] = f2bf(acc);
            }
        }
        __syncthreads();

        for (int task = tid; task < 8 * 81; task += 256) {
            int gl = task / 81, patch = task - gl * 81;
            int py = (patch / 9) * 2, px = (patch - (patch / 9) * 9) * 2;
            float bias = s_b3a[gl];
            float a00 = bias, a01 = bias, a10 = bias, a11 = bias;
#pragma unroll
            for (int j = 0; j < 3; ++j) {
                int lc = (gl < 4) ? (3 * gl + j) : (12 + 3 * (gl - 4) + j);
                const u32* base = (const u32*)&s_xc[lc][0];
                float win[4][4];
#pragma unroll
                for (int r = 0; r < 4; ++r) {
                    int e = (py + r) * R20 + px;
                    u32 u0 = base[e >> 1];
                    u32 u1 = base[(e >> 1) + 1];
                    win[r][0] = bflo(u0); win[r][1] = bfhi(u0);
                    win[r][2] = bflo(u1); win[r][3] = bfhi(u1);
                }
#pragma unroll
                for (int ky = 0; ky < 3; ++ky)
#pragma unroll
                    for (int kx = 0; kx < 3; ++kx) {
                        float wgt = s_wd3a[gl][j * 9 + ky * 3 + kx];
                        a00 = fmaf(wgt, win[ky][kx], a00);
                        a01 = fmaf(wgt, win[ky][kx + 1], a01);
                        a10 = fmaf(wgt, win[ky + 1][kx], a10);
                        a11 = fmaf(wgt, win[ky + 1][kx + 1], a11);
                    }
            }
            int gy0 = oy0 - 1 + py, gx0 = ox0 - 1 + px;
            bool vy0 = (unsigned)gy0 < 256u, vy1 = (unsigned)(gy0 + 1) < 256u;
            bool vx0 = (unsigned)gx0 < 256u, vx1 = (unsigned)(gx0 + 1) < 256u;
            float* drow = &s_d3a[gl][py * R18 + px];
            drow[0]       = (vy0 && vx0) ? a00 : 0.f;
            drow[1]       = (vy0 && vx1) ? a01 : 0.f;
            drow[R18]     = (vy1 && vx0) ? a10 : 0.f;
            drow[R18 + 1] = (vy1 && vx1) ? a11 : 0.f;
        }

        for (int task = tid; task < 8 * 64; task += 256) {
            int gl = task >> 6, patch = task & 63;
            int py = (patch >> 3) * 2, px = (patch & 7) * 2;
            float bias = s_b1[gl];
            float a00 = bias, a01 = bias, a10 = bias, a11 = bias;
#pragma unroll
            for (int j = 0; j < 3; ++j) {
                int lc = (gl < 4) ? (3 * gl + j) : (12 + 3 * (gl - 4) + j);
                const u32* base = (const u32*)&s_xc[lc][0];
                float win[4][4];
#pragma unroll
                for (int r = 0; r < 4; ++r) {
                    int e = (py + 1 + r) * R20 + px;
                    u32 u0 = base[e >> 1];
                    u32 u1 = base[(e >> 1) + 1];
                    u32 u2 = base[(e >> 1) + 2];
                    win[r][0] = bfhi(u0); win[r][1] = bflo(u1);
                    win[r][2] = bfhi(u1); win[r][3] = bflo(u2);
                }
#pragma unroll
                for (int ky = 0; ky < 3; ++ky)
#pragma unroll
                    for (int kx = 0; kx < 3; ++kx) {
                        float wgt = s_wd1[gl][j * 9 + ky * 3 + kx];
                        a00 = fmaf(wgt, win[ky][kx], a00);
                        a01 = fmaf(wgt, win[ky][kx + 1], a01);
                        a10 = fmaf(wgt, win[ky + 1][kx], a10);
                        a11 = fmaf(wgt, win[ky + 1][kx + 1], a11);
                    }
            }
            float* drow = &s_d1[gl][py * T + px];
            drow[0] = a00; drow[1] = a01; drow[T] = a10; drow[T + 1] = a11;
        }
        __syncthreads();

        for (int task = tid; task < 8 * 64; task += 256) {
            int gl = task >> 6, patch = task & 63;
            int py = (patch >> 3) * 2, px = (patch & 7) * 2;
            float bias = s_b3b[gl];
            float a00 = bias, a01 = bias, a10 = bias, a11 = bias;
            float win[4][4];
#pragma unroll
            for (int r = 0; r < 4; ++r) {
                int e = (py + r) * R18 + px;
                float2 f0 = *(const float2*)&s_d3a[gl][e];
                float2 f1 = *(const float2*)&s_d3a[gl][e + 2];
                win[r][0] = f0.x; win[r][1] = f0.y;
                win[r][2] = f1.x; win[r][3] = f1.y;
            }
#pragma unroll
            for (int ky = 0; ky < 3; ++ky)
#pragma unroll
                for (int kx = 0; kx < 3; ++kx) {
                    float wgt = s_wd3b[gl][ky * 3 + kx];
                    a00 = fmaf(wgt, win[ky][kx], a00);
                    a01 = fmaf(wgt, win[ky][kx + 1], a01);
                    a10 = fmaf(wgt, win[ky + 1][kx], a10);
                    a11 = fmaf(wgt, win[ky + 1][kx + 1], a11);
                }
            float* drow = &s_d3[gl][py * T + px];
            drow[0] = a00; drow[1] = a01; drow[T] = a10; drow[T + 1] = a11;
        }
        __syncthreads();

#pragma unroll
        for (int jp = 0; jp < 2; ++jp) {
            int j0 = 2 * jp;
            float g1a = gelu_exact(s_d1[j0][tid])     * s_d1[j0 + 4][tid];
            float g1b = gelu_exact(s_d1[j0 + 1][tid]) * s_d1[j0 + 5][tid];
            float g2a = gelu_exact(s_d3[j0][tid])     * s_d3[j0 + 4][tid];
            float g2b = gelu_exact(s_d3[j0 + 1][tid]) * s_d3[j0 + 5][tid];
            int c = c0 + j0;
#pragma unroll
            for (int o = 0; o < 32; ++o) {
                float2 wL = *(const float2*)(w_out + o * 64 + c);
                accL[o] = fmaf(wL.x, g1a, accL[o]);
                accL[o] = fmaf(wL.y, g1b, accL[o]);
                float2 wH = *(const float2*)(w_out + (o + 32) * 64 + c);
                accH[o] = fmaf(wH.x, g2a, accH[o]);
                accH[o] = fmaf(wH.y, g2b, accH[o]);
            }
        }
    }

    {
        int py = tid >> 4, pxx = tid & 15;
        size_t obase = (size_t)b * 64 * HW
                     + (size_t)(oy0 + py) * 256 + (ox0 + pxx);
#pragma unroll
        for (int o = 0; o < 32; ++o) {
            outp[obase + (size_t)o * HW]        = accL[o] + b_out[o];
            outp[obase + (size_t)(o + 32) * HW] = accH[o] + b_out[o + 32];
        }
    }
}

extern "C" void kernel_launch(void* const* d_in, const int* in_sizes, int n_in,
                              void* d_out, int out_size, void* d_ws, size_t ws_size,
                              hipStream_t stream) {
    (void)in_sizes; (void)n_in; (void)out_size;
    const float* xin    = (const float*)d_in[0];
    const float* pnin   = (const float*)d_in[1];
    const float* w_in   = (const float*)d_in[2];
    const float* b_in   = (const float*)d_in[3];
    const float* w_pn   = (const float*)d_in[4];
    const float* b_pn   = (const float*)d_in[5];
    const float* w_dw1  = (const float*)d_in[6];
    const float* b_dw1  = (const float*)d_in[7];
    const float* w_dw3a = (const float*)d_in[8];
    const float* b_dw3a = (const float*)d_in[9];
    const float* w_dw3b = (const float*)d_in[10];
    const float* b_dw3b = (const float*)d_in[11];
    const float* w_out  = (const float*)d_in[12];
    const float* b_out  = (const float*)d_in[13];
    float* outp = (float*)d_out;

    if (ws_size >= XC_BYTES) {
        u16* xc = (u16*)d_ws;
        dim3 g1(256, 4), b1(256);    // 4 tiles of 64 px per block
        k1_proj_mfma<<<g1, b1, 0, stream>>>(xin, pnin, w_in, b_in, w_pn, b_pn, xc);
        dim3 g2(16, 16, 4), b2(512);
        k2_spatial<<<g2, b2, 0, stream>>>(xc, w_dw1, b_dw1, w_dw3a, b_dw3a,
                                          w_dw3b, b_dw3b, w_out, b_out, outp);
    } else {
        dim3 grid(16, 16, 4), blk(256);
        ffd_fused<<<grid, blk, 0, stream>>>(xin, pnin, w_in, b_in, w_pn, b_pn,
                                            w_dw1, b_dw1, w_dw3a, b_dw3a,
                                            w_dw3b, b_dw3b, w_out, b_out, outp);
    }
}

// Round 11
// 463.739 us; speedup vs baseline: 1.1301x; 1.1301x over previous
//
#include <hip/hip_runtime.h>
#include <hip/hip_bf16.h>

// Two-phase FeedForward_denoise — BEST-MEASURED CONFIG (r6, 463 us):
//   K1 (r5): MFMA split-bf16 GEMM, 4 pixel-tiles/block, LDS double buffer,
//       weights loaded once, deferred epilogue (acc[4][4] held across the
//       tile so all 96 MFMAs pipeline), direct scattered 8B stores. ~174 us.
//       (r8 staged-split: neutral. r10 per-pj acc + immediate stores: 235 us
//        — store/pack work entered the MFMA critical path. Both reverted.)
//   K2 (r6): u16 LDS halo, 2x2-patch B phases, halo prefetch (T14),
//       erf_fast, gate products -> s_g ring, project_out via split-bf16
//       MFMA passes at chunks 7/15. ~289 us, reproduced 3x.
//       (r5 lane-pair fusion: 534 us, bank conflicts. r7 VGPR-capped
//        occupancy: spill, 1 GB HBM. r9 LDS-shrink: VGPR 108, 302 us.
//        All reverted.)
// Fallback to the fully-fused kernel if ws_size < 201 MB.

#define T 16
#define R20 20
#define R18 18
#define HW 65536
#define XC_BYTES ((size_t)4 * 16 * HW * 24 * 2)

typedef unsigned short u16;
typedef unsigned int u32;

typedef __attribute__((ext_vector_type(8))) short bf16x8;
typedef __attribute__((ext_vector_type(4))) float f32x4;
typedef __attribute__((ext_vector_type(2))) float f32x2;

__device__ __forceinline__ float bflo(u32 w) {
    union { u32 i; float f; } v; v.i = w << 16; return v.f;
}
__device__ __forceinline__ float bfhi(u32 w) {
    union { u32 i; float f; } v; v.i = w & 0xffff0000u; return v.f;
}
__device__ __forceinline__ float bf2f(u16 u) {
    union { u32 i; float f; } v; v.i = ((u32)u) << 16; return v.f;
}
__device__ __forceinline__ u16 f2bf(float f) {
    union { float f; u32 i; } v; v.f = f;
    u32 x = v.i;
    u32 r = (x + 0x7fffu + ((x >> 16) & 1u)) >> 16;
    return (u16)r;
}
__device__ __forceinline__ u32 f2bf2(float a, float b) {
    return (u32)f2bf(a) | ((u32)f2bf(b) << 16);
}
__device__ __forceinline__ float gelu_exact(float v) {
    return 0.5f * v * (1.0f + erff(v * 0.70710678118654752f));
}
// Branch-free erf, A&S 7.1.26 (|err| ~1e-6) — inputs bf16-rounded already.
__device__ __forceinline__ float erf_fast(float x) {
    float ax = fabsf(x);
    float t = __builtin_amdgcn_rcpf(fmaf(0.3275911f, ax, 1.0f));
    float p = fmaf(t, 1.061405429f, -1.453152027f);
    p = fmaf(t, p, 1.421413741f);
    p = fmaf(t, p, -0.284496736f);
    p = fmaf(t, p, 0.254829592f);
    p = p * t;
    float e = __expf(-ax * ax);
    float r = fmaf(-p, e, 1.0f);
    return copysignf(r, x);
}
__device__ __forceinline__ float gelu_fast(float v) {
    return 0.5f * v * (1.0f + erf_fast(v * 0.70710678118654752f));
}

// Exact split of two fp32 into packed-bf16 hi (truncated) and lo (residual).
__device__ __forceinline__ void pack_pair(float a, float b, u32& hi, u32& lo) {
    union { float f; u32 i; } ua, ub, ha, hb, la, lb;
    ua.f = a; ub.f = b;
    ha.i = ua.i & 0xffff0000u;
    hb.i = ub.i & 0xffff0000u;
    hi = (ha.i >> 16) | hb.i;
    la.f = a - ha.f;
    lb.f = b - hb.f;
    lo = (la.i >> 16) | (lb.i & 0xffff0000u);
}

// ---------------------------------------------------------------------------
// K1: MFMA split-bf16 GEMM, 4 tiles/block, LDS dbuf, direct global stores.
// ---------------------------------------------------------------------------
__global__ __launch_bounds__(256, 2)
void k1_proj_mfma(const float* __restrict__ xin,   // [4][64][256][256]
                  const float* __restrict__ pnin,  // [4][2][256][256]
                  const float* __restrict__ w_in,  // [256][64]
                  const float* __restrict__ b_in,  // [256]
                  const float* __restrict__ w_pn,  // [128][2]
                  const float* __restrict__ b_pn,  // [128]
                  u16* __restrict__ xc)            // [4][16][HW][24] bf16
{
    __shared__ float s_x[2][64][65];               // 2 x 16.6 KB
    __shared__ float s_bin[256];

    const int tid  = threadIdx.x;
    const int b    = blockIdx.y;
    const int pxbase = blockIdx.x * 256;           // 4 tiles of 64 px
    const int lane = tid & 63;
    const int wid  = tid >> 6;
    const int lr   = lane & 15;        // MFMA row/col-in-16 index
    const int lh   = lane >> 4;        // MFMA k-group index
    const int CB   = wid * 64;         // this wave's channel base
    const int wu   = __builtin_amdgcn_readfirstlane(wid);

    s_bin[tid] = b_in[tid];

    // ---- w fragments: hi/lo bf16, loaded once per block -------------------
    bf16x8 whi[4][2], wlo[4][2];
#pragma unroll
    for (int ci = 0; ci < 4; ++ci)
#pragma unroll
        for (int ks = 0; ks < 2; ++ks) {
            const float* wp = w_in + (size_t)(CB + 16 * ci + lr) * 64
                            + 32 * ks + 8 * lh;
            float4 A0 = *(const float4*)wp;
            float4 A1 = *(const float4*)(wp + 4);
            union { u32 u[4]; bf16x8 v; } H, L;
            pack_pair(A0.x, A0.y, H.u[0], L.u[0]);
            pack_pair(A0.z, A0.w, H.u[1], L.u[1]);
            pack_pair(A1.x, A1.y, H.u[2], L.u[2]);
            pack_pair(A1.z, A1.w, H.u[3], L.u[3]);
            whi[ci][ks] = H.v; wlo[ci][ks] = L.v;
        }

    // ---- prologue: stage tile 0 -------------------------------------------
    {
        const float* xb = xin + (size_t)b * 64 * HW + pxbase;
#pragma unroll
        for (int i = 0; i < 4; ++i) {
            int idx = tid + 256 * i;
            int row = idx >> 4, seg = (idx & 15) * 4;
            float4 v = *(const float4*)(xb + (size_t)row * HW + seg);
            s_x[0][row][seg + 0] = v.x; s_x[0][row][seg + 1] = v.y;
            s_x[0][row][seg + 2] = v.z; s_x[0][row][seg + 3] = v.w;
        }
    }

    int cur = 0;
#pragma unroll 1
    for (int t = 0; t < 4; ++t) {
        const int px0 = pxbase + t * 64;

        // issue next-tile global loads (land after this tile's compute)
        float4 nx[4];
        if (t < 3) {
            const float* xb = xin + (size_t)b * 64 * HW + px0 + 64;
#pragma unroll
            for (int i = 0; i < 4; ++i) {
                int idx = tid + 256 * i;
                int row = idx >> 4, seg = (idx & 15) * 4;
                nx[i] = *(const float4*)(xb + (size_t)row * HW + seg);
            }
        }
        float p0 = pnin[(size_t)b * 2 * HW + px0 + lane];
        float p1 = pnin[(size_t)b * 2 * HW + HW + px0 + lane];

        __syncthreads();   // s_x[cur] fully staged (prologue or prev tail)

        // ---- pn projection: direct 8B stores ------------------------------
#pragma unroll
        for (int q = 0; q < 8; ++q) {
            int k = 32 * wu + 4 * q;           // wave-uniform quad base, <128
            int c = k / 12, l = k - 12 * c;    // l in {0,4,8}
            float v0 = fmaf(w_pn[2*k+0], p0, fmaf(w_pn[2*k+1], p1, b_pn[k+0]));
            float v1 = fmaf(w_pn[2*k+2], p0, fmaf(w_pn[2*k+3], p1, b_pn[k+1]));
            float v2 = fmaf(w_pn[2*k+4], p0, fmaf(w_pn[2*k+5], p1, b_pn[k+2]));
            float v3 = fmaf(w_pn[2*k+6], p0, fmaf(w_pn[2*k+7], p1, b_pn[k+3]));
            uint2 val;
            val.x = f2bf2(v0, v1);
            val.y = f2bf2(v2, v3);
            *(uint2*)(xc + ((size_t)(b * 16 + c) * HW + px0 + lane) * 24 + l) = val;
        }

        // ---- MFMA: acc[ci][pj] = W[64ch x 64k] * X[64k x 64px] ------------
        f32x4 acc[4][4];
#pragma unroll
        for (int ci = 0; ci < 4; ++ci)
#pragma unroll
            for (int pj = 0; pj < 4; ++pj)
                acc[ci][pj] = (f32x4){0.f, 0.f, 0.f, 0.f};

#pragma unroll
        for (int pj = 0; pj < 4; ++pj) {
            bf16x8 xh[2], xl[2];
#pragma unroll
            for (int ks = 0; ks < 2; ++ks) {
                const int rb = 32 * ks + 8 * lh;
                const int cb = 16 * pj + lr;
                float x0 = s_x[cur][rb + 0][cb], x1 = s_x[cur][rb + 1][cb];
                float x2 = s_x[cur][rb + 2][cb], x3 = s_x[cur][rb + 3][cb];
                float x4 = s_x[cur][rb + 4][cb], x5 = s_x[cur][rb + 5][cb];
                float x6 = s_x[cur][rb + 6][cb], x7 = s_x[cur][rb + 7][cb];
                union { u32 u[4]; bf16x8 v; } H, L;
                pack_pair(x0, x1, H.u[0], L.u[0]);
                pack_pair(x2, x3, H.u[1], L.u[1]);
                pack_pair(x4, x5, H.u[2], L.u[2]);
                pack_pair(x6, x7, H.u[3], L.u[3]);
                xh[ks] = H.v; xl[ks] = L.v;
            }
#pragma unroll
            for (int ci = 0; ci < 4; ++ci) {
#pragma unroll
                for (int ks = 0; ks < 2; ++ks) {
                    acc[ci][pj] = __builtin_amdgcn_mfma_f32_16x16x32_bf16(
                        whi[ci][ks], xh[ks], acc[ci][pj], 0, 0, 0);
                    acc[ci][pj] = __builtin_amdgcn_mfma_f32_16x16x32_bf16(
                        whi[ci][ks], xl[ks], acc[ci][pj], 0, 0, 0);
                    acc[ci][pj] = __builtin_amdgcn_mfma_f32_16x16x32_bf16(
                        wlo[ci][ks], xh[ks], acc[ci][pj], 0, 0, 0);
                }
            }
        }

        // ---- epilogue: bias + bf16 + direct stores ------------------------
#pragma unroll
        for (int ci = 0; ci < 4; ++ci) {
            const int kk = CB + 16 * ci + 4 * lh;
            float b0 = s_bin[kk + 0], b1 = s_bin[kk + 1];
            float b2 = s_bin[kk + 2], b3 = s_bin[kk + 3];
            int c, l;
            int kg = kk + 128;
            if (kg < 192) { c = kg / 12; l = kg - 12 * c; }
            else { int t2 = kg - 192; int cq = t2 / 12; c = cq; l = 12 + (t2 - 12 * cq); }
            u16* rec = xc + ((size_t)(b * 16 + c) * HW + px0) * 24 + l;
#pragma unroll
            for (int pj = 0; pj < 4; ++pj) {
                f32x4 a = acc[ci][pj];
                uint2 val;
                val.x = f2bf2(a[0] + b0, a[1] + b1);
                val.y = f2bf2(a[2] + b2, a[3] + b3);
                *(uint2*)(rec + (size_t)(16 * pj + lr) * 24) = val;
            }
        }

        // ---- tail: write prefetched tile into other buffer ----------------
        if (t < 3) {
#pragma unroll
            for (int i = 0; i < 4; ++i) {
                int idx = tid + 256 * i;
                int row = idx >> 4, seg = (idx & 15) * 4;
                float* d = &s_x[cur ^ 1][row][seg];
                d[0] = nx[i].x; d[1] = nx[i].y; d[2] = nx[i].z; d[3] = nx[i].w;
            }
            cur ^= 1;
        }
    }
}

// ---------------------------------------------------------------------------
// K2: spatial convs + gating; project_out via MFMA gate passes. (r6 verbatim)
// ---------------------------------------------------------------------------
__global__ __launch_bounds__(512, 2)
void k2_spatial(const u16* __restrict__ xc,       // [4][16][HW][24] bf16
                const float* __restrict__ w_dw1,  const float* __restrict__ b_dw1,
                const float* __restrict__ w_dw3a, const float* __restrict__ b_dw3a,
                const float* __restrict__ w_dw3b, const float* __restrict__ b_dw3b,
                const float* __restrict__ w_out,  const float* __restrict__ b_out,
                float* __restrict__ outp)         // [4][64][256][256]
{
    __shared__ __align__(8) u16 s_xc[24][R20 * R20];
    __shared__ __align__(8) u16 s_d3a[8][R18 * R18];
    __shared__ __align__(8) u16 s_d1[8][T * T];
    __shared__ __align__(8) u16 s_d3[8][T * T];
    __shared__ __align__(16) u16 s_g[2][256][40];  // [half][px][gate-col ring]
    __shared__ float s_wd1[8][27];
    __shared__ float s_wd3a[8][27];
    __shared__ float s_wd3b[8][9];
    __shared__ float s_b1[8], s_b3a[8], s_b3b[8];

    const int tid  = threadIdx.x;
    const int half = tid >> 8;          // wave-uniform (waves 0-3 vs 4-7)
    const int pix  = tid & 255;
    const int ox0 = blockIdx.x * T;
    const int oy0 = blockIdx.y * T;
    const int b   = blockIdx.z;

    // MFMA pass role: wave w -> gh (which gate half), cw (ch-tile),
    // ph (px-half). Out rows [32gh+16cw, +16), px-tiles 8ph..8ph+7.
    const int w    = tid >> 6;
    const int lane = tid & 63;
    const int lr   = lane & 15;
    const int lh   = lane >> 4;
    const int gh   = w >> 2;
    const int cw   = (w >> 1) & 1;
    const int ph   = w & 1;

    // ---- halo prefetch state (chunk-invariant coords) ---------------------
    int hpy = tid / R20, hpx = tid - hpy * R20;     // meaningful for tid<400
    int hgy = oy0 - 2 + hpy, hgx = ox0 - 2 + hpx;
    const bool pvalid = (tid < 400) &&
                        ((unsigned)hgy < 256u) && ((unsigned)hgx < 256u);
    const u16* psrc = xc + ((size_t)(b * 16) * HW
                            + (pvalid ? (hgy * 256 + hgx) : 0)) * 24;
    uint4 pv0, pv1, pv2;
    pv0 = pv1 = pv2 = make_uint4(0, 0, 0, 0);
    if (pvalid) {
        const uint4* s = (const uint4*)psrc;
        pv0 = s[0]; pv1 = s[1]; pv2 = s[2];
    }

    f32x4 acc[8];      // 8 px-tiles of this wave's 16-ch out slice
#pragma unroll
    for (int t = 0; t < 8; ++t) acc[t] = (f32x4){0.f, 0.f, 0.f, 0.f};

    for (int chunk = 0; chunk < 16; ++chunk) {
        const int c0 = chunk * 4;
        __syncthreads();   // protect s_* reuse across chunks

        // ---- Phase W: stage chunk weights into LDS -------------------------
        {
            int t = tid;
            if (t < 216) {
                int gl = t / 27, idx = t - gl * 27;
                int g = (gl < 4) ? (c0 + gl) : (c0 + 60 + gl);
                s_wd1[gl][idx] = w_dw1[g * 27 + idx];
            } else if (t < 432) {
                int t2 = t - 216;
                int gl = t2 / 27, idx = t2 - gl * 27;
                int g = (gl < 4) ? (c0 + gl) : (c0 + 60 + gl);
                s_wd3a[gl][idx] = w_dw3a[g * 27 + idx];
            } else if (t < 504) {
                int t2 = t - 432;
                int gl = t2 / 9, idx = t2 - gl * 9;
                int g = (gl < 4) ? (c0 + gl) : (c0 + 60 + gl);
                s_wd3b[gl][idx] = w_dw3b[g * 9 + idx];
            } else if (t < 512) {
                int gl = t - 504;
                int g = (gl < 4) ? (c0 + gl) : (c0 + 60 + gl);
                s_b1[gl]  = b_dw1[g];
                s_b3a[gl] = b_dw3a[g];
                s_b3b[gl] = b_dw3b[g];
            }
        }

        // ---- Phase A: write prefetched halo, then issue chunk+1 loads ------
        if (tid < 400) {
            union { uint4 q[3]; u16 h[24]; } v;
            v.q[0] = pv0; v.q[1] = pv1; v.q[2] = pv2;
#pragma unroll
            for (int l = 0; l < 24; ++l) s_xc[l][tid] = v.h[l];
        }
        {
            uint4 n0, n1, n2;
            n0 = n1 = n2 = make_uint4(0, 0, 0, 0);
            if (pvalid && chunk < 15) {
                const uint4* s = (const uint4*)(psrc
                                 + (size_t)(chunk + 1) * HW * 24);
                n0 = s[0]; n1 = s[1]; n2 = s[2];
            }
            pv0 = n0; pv1 = n1; pv2 = n2;   // waitcnt lands at next-iter use
        }
        __syncthreads();

        // ---- Phase B1a: d3a (grouped 3x3) over 18x18, 2x2 per thread -------
        for (int task = tid; task < 8 * 81; task += 512) {
            int gl = task / 81, patch = task - gl * 81;
            int py = (patch / 9) * 2, px = (patch - (patch / 9) * 9) * 2;
            float bias = s_b3a[gl];
            float a00 = bias, a01 = bias, a10 = bias, a11 = bias;
#pragma unroll
            for (int j = 0; j < 3; ++j) {
                int lc = (gl < 4) ? (3 * gl + j) : (12 + 3 * (gl - 4) + j);
                const u32* base = (const u32*)&s_xc[lc][0];
                float win[4][4];
#pragma unroll
                for (int r = 0; r < 4; ++r) {
                    int e = (py + r) * R20 + px;   // even
                    u32 u0 = base[e >> 1];
                    u32 u1 = base[(e >> 1) + 1];
                    win[r][0] = bflo(u0); win[r][1] = bfhi(u0);
                    win[r][2] = bflo(u1); win[r][3] = bfhi(u1);
                }
#pragma unroll
                for (int ky = 0; ky < 3; ++ky)
#pragma unroll
                    for (int kx = 0; kx < 3; ++kx) {
                        float wgt = s_wd3a[gl][j * 9 + ky * 3 + kx];
                        a00 = fmaf(wgt, win[ky][kx], a00);
                        a01 = fmaf(wgt, win[ky][kx + 1], a01);
                        a10 = fmaf(wgt, win[ky + 1][kx], a10);
                        a11 = fmaf(wgt, win[ky + 1][kx + 1], a11);
                    }
            }
            int gy0 = oy0 - 1 + py, gx0 = ox0 - 1 + px;
            bool vy0 = (unsigned)gy0 < 256u, vy1 = (unsigned)(gy0 + 1) < 256u;
            bool vx0 = (unsigned)gx0 < 256u, vx1 = (unsigned)(gx0 + 1) < 256u;
            u16* drow = &s_d3a[gl][py * R18 + px];
            drow[0]       = (vy0 && vx0) ? f2bf(a00) : (u16)0;
            drow[1]       = (vy0 && vx1) ? f2bf(a01) : (u16)0;
            drow[R18]     = (vy1 && vx0) ? f2bf(a10) : (u16)0;
            drow[R18 + 1] = (vy1 && vx1) ? f2bf(a11) : (u16)0;
        }

        // ---- Phase B1b: d1 (grouped 3x3), one 2x2 task per thread ----------
        {
            int gl = tid >> 6, patch = tid & 63;
            int py = (patch >> 3) * 2, px = (patch & 7) * 2;
            float bias = s_b1[gl];
            float a00 = bias, a01 = bias, a10 = bias, a11 = bias;
#pragma unroll
            for (int j = 0; j < 3; ++j) {
                int lc = (gl < 4) ? (3 * gl + j) : (12 + 3 * (gl - 4) + j);
                const u32* base = (const u32*)&s_xc[lc][0];
                float win[4][4];
#pragma unroll
                for (int r = 0; r < 4; ++r) {
                    int e = (py + 1 + r) * R20 + px;   // even; cols px+1..px+4
                    u32 u0 = base[e >> 1];
                    u32 u1 = base[(e >> 1) + 1];
                    u32 u2 = base[(e >> 1) + 2];
                    win[r][0] = bfhi(u0); win[r][1] = bflo(u1);
                    win[r][2] = bfhi(u1); win[r][3] = bflo(u2);
                }
#pragma unroll
                for (int ky = 0; ky < 3; ++ky)
#pragma unroll
                    for (int kx = 0; kx < 3; ++kx) {
                        float wgt = s_wd1[gl][j * 9 + ky * 3 + kx];
                        a00 = fmaf(wgt, win[ky][kx], a00);
                        a01 = fmaf(wgt, win[ky][kx + 1], a01);
                        a10 = fmaf(wgt, win[ky + 1][kx], a10);
                        a11 = fmaf(wgt, win[ky + 1][kx + 1], a11);
                    }
            }
            u16* drow = &s_d1[gl][py * T + px];
            drow[0] = f2bf(a00); drow[1] = f2bf(a01);
            drow[T] = f2bf(a10); drow[T + 1] = f2bf(a11);
        }
        __syncthreads();

        // ---- Phase B2: d3 = depthwise 3x3 over d3a, one task per thread ----
        {
            int gl = tid >> 6, patch = tid & 63;
            int py = (patch >> 3) * 2, px = (patch & 7) * 2;
            float bias = s_b3b[gl];
            float a00 = bias, a01 = bias, a10 = bias, a11 = bias;
            float win[4][4];
            const u32* base = (const u32*)&s_d3a[gl][0];
#pragma unroll
            for (int r = 0; r < 4; ++r) {
                int e = (py + r) * R18 + px;   // even
                u32 u0 = base[e >> 1];
                u32 u1 = base[(e >> 1) + 1];
                win[r][0] = bflo(u0); win[r][1] = bfhi(u0);
                win[r][2] = bflo(u1); win[r][3] = bfhi(u1);
            }
#pragma unroll
            for (int ky = 0; ky < 3; ++ky)
#pragma unroll
                for (int kx = 0; kx < 3; ++kx) {
                    float wgt = s_wd3b[gl][ky * 3 + kx];
                    a00 = fmaf(wgt, win[ky][kx], a00);
                    a01 = fmaf(wgt, win[ky][kx + 1], a01);
                    a10 = fmaf(wgt, win[ky + 1][kx], a10);
                    a11 = fmaf(wgt, win[ky + 1][kx + 1], a11);
                }
            u16* drow = &s_d3[gl][py * T + px];
            drow[0] = f2bf(a00); drow[1] = f2bf(a01);
            drow[T] = f2bf(a10); drow[T + 1] = f2bf(a11);
        }
        __syncthreads();

        // ---- Phase G: gate products -> s_g (bf16), one 8B write -----------
        {
            const u16* sD = (half == 0) ? &s_d1[0][0] : &s_d3[0][0];
            float ga = gelu_fast(bf2f(sD[0 * 256 + pix])) * bf2f(sD[4 * 256 + pix]);
            float gb = gelu_fast(bf2f(sD[1 * 256 + pix])) * bf2f(sD[5 * 256 + pix]);
            float gc = gelu_fast(bf2f(sD[2 * 256 + pix])) * bf2f(sD[6 * 256 + pix]);
            float gd = gelu_fast(bf2f(sD[3 * 256 + pix])) * bf2f(sD[7 * 256 + pix]);
            uint2 val;
            val.x = f2bf2(ga, gb);
            val.y = f2bf2(gc, gd);
            *(uint2*)&s_g[half][pix][c0 & 31] = val;
        }

        // ---- MFMA pass after chunks 7 and 15 (gate cols 0..31 / 32..63) ---
        if (chunk == 7 || chunk == 15) {
            __syncthreads();   // s_g complete for this 32-col window
            const int p = chunk >> 3;
            // A-frag: w_out rows [32gh+16cw+lr], cols 32p+8lh .. +7 (split)
            const float* wp = w_out + (size_t)(32 * gh + 16 * cw + lr) * 64
                            + 32 * p + 8 * lh;
            float4 A0 = *(const float4*)wp;
            float4 A1 = *(const float4*)(wp + 4);
            union { u32 u[4]; bf16x8 v; } H, L;
            pack_pair(A0.x, A0.y, H.u[0], L.u[0]);
            pack_pair(A0.z, A0.w, H.u[1], L.u[1]);
            pack_pair(A1.x, A1.y, H.u[2], L.u[2]);
            pack_pair(A1.z, A1.w, H.u[3], L.u[3]);
            bf16x8 Ah = H.v, Al = L.v;
#pragma unroll
            for (int t = 0; t < 8; ++t) {
                int pt = 8 * ph + t;
                bf16x8 Bv = *(const bf16x8*)&s_g[gh][16 * pt + lr][8 * lh];
                acc[t] = __builtin_amdgcn_mfma_f32_16x16x32_bf16(Ah, Bv, acc[t], 0, 0, 0);
                acc[t] = __builtin_amdgcn_mfma_f32_16x16x32_bf16(Al, Bv, acc[t], 0, 0, 0);
            }
        }
    }

    // ---- Epilogue: bias + fp32 store --------------------------------------
    // D-frag: value r of px-tile t is out[o = 32gh+16cw+4lh+r][px = 16pt+lr]
    {
        const int o = 32 * gh + 16 * cw + 4 * lh;
        float b0 = b_out[o + 0], b1 = b_out[o + 1];
        float b2 = b_out[o + 2], b3 = b_out[o + 3];
#pragma unroll
        for (int t = 0; t < 8; ++t) {
            int pt = 8 * ph + t;
            size_t base = (size_t)b * 64 * HW + (size_t)o * HW
                        + (size_t)(oy0 + pt) * 256 + (ox0 + lr);
            outp[base + 0 * HW] = acc[t][0] + b0;
            outp[base + 1 * HW] = acc[t][1] + b1;
            outp[base + 2 * HW] = acc[t][2] + b2;
            outp[base + 3 * HW] = acc[t][3] + b3;
        }
    }
}

// ---------------------------------------------------------------------------
// Fallback: fully-fused kernel (used only if ws_size < 201 MB).
// ---------------------------------------------------------------------------
__global__ __launch_bounds__(256, 2)
void ffd_fused(const float* __restrict__ xin, const float* __restrict__ pnin,
               const float* __restrict__ w_in, const float* __restrict__ b_in,
               const float* __restrict__ w_pn, const float* __restrict__ b_pn,
               const float* __restrict__ w_dw1, const float* __restrict__ b_dw1,
               const float* __restrict__ w_dw3a, const float* __restrict__ b_dw3a,
               const float* __restrict__ w_dw3b, const float* __restrict__ b_dw3b,
               const float* __restrict__ w_out, const float* __restrict__ b_out,
               float* __restrict__ outp)
{
    __shared__ __align__(8) u16 s_xc[24][R20 * R20];
    __shared__ __align__(8) float s_d3a[8][R18 * R18];
    __shared__ float s_d1[8][T * T];
    __shared__ float s_d3[8][T * T];
    __shared__ float s_wd1[8][27];
    __shared__ float s_wd3a[8][27];
    __shared__ float s_wd3b[8][9];
    __shared__ float s_b1[8], s_b3a[8], s_b3b[8];

    const int tid = threadIdx.x;
    const int ox0 = blockIdx.x * T;
    const int oy0 = blockIdx.y * T;
    const int b   = blockIdx.z;

    float accL[32], accH[32];
#pragma unroll
    for (int o = 0; o < 32; ++o) { accL[o] = 0.f; accH[o] = 0.f; }

    for (int chunk = 0; chunk < 16; ++chunk) {
        const int c0 = chunk * 4;
        __syncthreads();

        for (int t = tid; t < 512; t += 256) {
            if (t < 216) {
                int gl = t / 27, idx = t - gl * 27;
                int g = (gl < 4) ? (c0 + gl) : (c0 + 60 + gl);
                s_wd1[gl][idx] = w_dw1[g * 27 + idx];
            } else if (t < 432) {
                int t2 = t - 216;
                int gl = t2 / 27, idx = t2 - gl * 27;
                int g = (gl < 4) ? (c0 + gl) : (c0 + 60 + gl);
                s_wd3a[gl][idx] = w_dw3a[g * 27 + idx];
            } else if (t < 504) {
                int t2 = t - 432;
                int gl = t2 / 9, idx = t2 - gl * 9;
                int g = (gl < 4) ? (c0 + gl) : (c0 + 60 + gl);
                s_wd3b[gl][idx] = w_dw3b[g * 9 + idx];
            } else {
                int gl = t - 504;
                int g = (gl < 4) ? (c0 + gl) : (c0 + 60 + gl);
                s_b1[gl]  = b_dw1[g];
                s_b3a[gl] = b_dw3a[g];
                s_b3b[gl] = b_dw3b[g];
            }
        }

        for (int p = tid; p < R20 * R20; p += 256) {
            int py = p / R20, px = p - py * R20;
            int gy = oy0 - 2 + py, gx = ox0 - 2 + px;
            if ((unsigned)gy >= 256u || (unsigned)gx >= 256u) {
#pragma unroll 1
                for (int l = 0; l < 24; ++l) s_xc[l][p] = 0;
                continue;
            }
            const int off = gy * 256 + gx;
            float xr[64];
            const float* xp = xin + (size_t)b * 64 * HW + off;
#pragma unroll
            for (int c = 0; c < 64; ++c) xr[c] = xp[(size_t)c * HW];
            float p0 = 0.f, p1 = 0.f;
            if (3 * c0 < 128) {
                const float* pp = pnin + (size_t)b * 2 * HW + off;
                p0 = pp[0]; p1 = pp[HW];
            }
#pragma unroll 1
            for (int l = 0; l < 24; ++l) {
                int k = (l < 12) ? (3 * c0 + l) : (3 * c0 + 192 + (l - 12));
                float acc;
                if (k < 128) {
                    acc = b_pn[k] + w_pn[2 * k] * p0 + w_pn[2 * k + 1] * p1;
                } else {
                    int kk = k - 128;
                    acc = b_in[kk];
                    const float2* wr = (const float2*)(w_in + kk * 64);
#pragma unroll
                    for (int i = 0; i < 32; ++i) {
                        float2 w2 = wr[i];
                        acc = fmaf(w2.x, xr[2 * i], acc);
                        acc = fmaf(w2.y, xr[2 * i + 1], acc);
                    }
                }
                s_xc[l][p] = f2bf(acc);
            }
        }
        __syncthreads();

        for (int task = tid; task < 8 * 81; task += 256) {
            int gl = task / 81, patch = task - gl * 81;
            int py = (patch / 9) * 2, px = (patch - (patch / 9) * 9) * 2;
            float bias = s_b3a[gl];
            float a00 = bias, a01 = bias, a10 = bias, a11 = bias;
#pragma unroll
            for (int j = 0; j < 3; ++j) {
                int lc = (gl < 4) ? (3 * gl + j) : (12 + 3 * (gl - 4) + j);
                const u32* base = (const u32*)&s_xc[lc][0];
                float win[4][4];
#pragma unroll
                for (int r = 0; r < 4; ++r) {
                    int e = (py + r) * R20 + px;
                    u32 u0 = base[e >> 1];
                    u32 u1 = base[(e >> 1) + 1];
                    win[r][0] = bflo(u0); win[r][1] = bfhi(u0);
                    win[r][2] = bflo(u1); win[r][3] = bfhi(u1);
                }
#pragma unroll
                for (int ky = 0; ky < 3; ++ky)
#pragma unroll
                    for (int kx = 0; kx < 3; ++kx) {
                        float wgt = s_wd3a[gl][j * 9 + ky * 3 + kx];
                        a00 = fmaf(wgt, win[ky][kx], a00);
                        a01 = fmaf(wgt, win[ky][kx + 1], a01);
                        a10 = fmaf(wgt, win[ky + 1][kx], a10);
                        a11 = fmaf(wgt, win[ky + 1][kx + 1], a11);
                    }
            }
            int gy0 = oy0 - 1 + py, gx0 = ox0 - 1 + px;
            bool vy0 = (unsigned)gy0 < 256u, vy1 = (unsigned)(gy0 + 1) < 256u;
            bool vx0 = (unsigned)gx0 < 256u, vx1 = (unsigned)(gx0 + 1) < 256u;
            float* drow = &s_d3a[gl][py * R18 + px];
            drow[0]       = (vy0 && vx0) ? a00 : 0.f;
            drow[1]       = (vy0 && vx1) ? a01 : 0.f;
            drow[R18]     = (vy1 && vx0) ? a10 : 0.f;
            drow[R18 + 1] = (vy1 && vx1) ? a11 : 0.f;
        }

        for (int task = tid; task < 8 * 64; task += 256) {
            int gl = task >> 6, patch = task & 63;
            int py = (patch >> 3) * 2, px = (patch & 7) * 2;
            float bias = s_b1[gl];
            float a00 = bias, a01 = bias, a10 = bias, a11 = bias;
#pragma unroll
            for (int j = 0; j < 3; ++j) {
                int lc = (gl < 4) ? (3 * gl + j) : (12 + 3 * (gl - 4) + j);
                const u32* base = (const u32*)&s_xc[lc][0];
                float win[4][4];
#pragma unroll
                for (int r = 0; r < 4; ++r) {
                    int e = (py + 1 + r) * R20 + px;
                    u32 u0 = base[e >> 1];
                    u32 u1 = base[(e >> 1) + 1];
                    u32 u2 = base[(e >> 1) + 2];
                    win[r][0] = bfhi(u0); win[r][1] = bflo(u1);
                    win[r][2] = bfhi(u1); win[r][3] = bflo(u2);
                }
#pragma unroll
                for (int ky = 0; ky < 3; ++ky)
#pragma unroll
                    for (int kx = 0; kx < 3; ++kx) {
                        float wgt = s_wd1[gl][j * 9 + ky * 3 + kx];
                        a00 = fmaf(wgt, win[ky][kx], a00);
                        a01 = fmaf(wgt, win[ky][kx + 1], a01);
                        a10 = fmaf(wgt, win[ky + 1][kx], a10);
                        a11 = fmaf(wgt, win[ky + 1][kx + 1], a11);
                    }
            }
            float* drow = &s_d1[gl][py * T + px];
            drow[0] = a00; drow[1] = a01; drow[T] = a10; drow[T + 1] = a11;
        }
        __syncthreads();

        for (int task = tid; task < 8 * 64; task += 256) {
            int gl = task >> 6, patch = task & 63;
            int py = (patch >> 3) * 2, px = (patch & 7) * 2;
            float bias = s_b3b[gl];
            float a00 = bias, a01 = bias, a10 = bias, a11 = bias;
            float win[4][4];
#pragma unroll
            for (int r = 0; r < 4; ++r) {
                int e = (py + r) * R18 + px;
                float2 f0 = *(const float2*)&s_d3a[gl][e];
                float2 f1 = *(const float2*)&s_d3a[gl][e + 2];
                win[r][0] = f0.x; win[r][1] = f0.y;
                win[r][2] = f1.x; win[r][3] = f1.y;
            }
#pragma unroll
            for (int ky = 0; ky < 3; ++ky)
#pragma unroll
                for (int kx = 0; kx < 3; ++kx) {
                    float wgt = s_wd3b[gl][ky * 3 + kx];
                    a00 = fmaf(wgt, win[ky][kx], a00);
                    a01 = fmaf(wgt, win[ky][kx + 1], a01);
                    a10 = fmaf(wgt, win[ky + 1][kx], a10);
                    a11 = fmaf(wgt, win[ky + 1][kx + 1], a11);
                }
            float* drow = &s_d3[gl][py * T + px];
            drow[0] = a00; drow[1] = a01; drow[T] = a10; drow[T + 1] = a11;
        }
        __syncthreads();

#pragma unroll
        for (int jp = 0; jp < 2; ++jp) {
            int j0 = 2 * jp;
            float g1a = gelu_exact(s_d1[j0][tid])     * s_d1[j0 + 4][tid];
            float g1b = gelu_exact(s_d1[j0 + 1][tid]) * s_d1[j0 + 5][tid];
            float g2a = gelu_exact(s_d3[j0][tid])     * s_d3[j0 + 4][tid];
            float g2b = gelu_exact(s_d3[j0 + 1][tid]) * s_d3[j0 + 5][tid];
            int c = c0 + j0;
#pragma unroll
            for (int o = 0; o < 32; ++o) {
                float2 wL = *(const float2*)(w_out + o * 64 + c);
                accL[o] = fmaf(wL.x, g1a, accL[o]);
                accL[o] = fmaf(wL.y, g1b, accL[o]);
                float2 wH = *(const float2*)(w_out + (o + 32) * 64 + c);
                accH[o] = fmaf(wH.x, g2a, accH[o]);
                accH[o] = fmaf(wH.y, g2b, accH[o]);
            }
        }
    }

    {
        int py = tid >> 4, pxx = tid & 15;
        size_t obase = (size_t)b * 64 * HW
                     + (size_t)(oy0 + py) * 256 + (ox0 + pxx);
#pragma unroll
        for (int o = 0; o < 32; ++o) {
            outp[obase + (size_t)o * HW]        = accL[o] + b_out[o];
            outp[obase + (size_t)(o + 32) * HW] = accH[o] + b_out[o + 32];
        }
    }
}

extern "C" void kernel_launch(void* const* d_in, const int* in_sizes, int n_in,
                              void* d_out, int out_size, void* d_ws, size_t ws_size,
                              hipStream_t stream) {
    (void)in_sizes; (void)n_in; (void)out_size;
    const float* xin    = (const float*)d_in[0];
    const float* pnin   = (const float*)d_in[1];
    const float* w_in   = (const float*)d_in[2];
    const float* b_in   = (const float*)d_in[3];
    const float* w_pn   = (const float*)d_in[4];
    const float* b_pn   = (const float*)d_in[5];
    const float* w_dw1  = (const float*)d_in[6];
    const float* b_dw1  = (const float*)d_in[7];
    const float* w_dw3a = (const float*)d_in[8];
    const float* b_dw3a = (const float*)d_in[9];
    const float* w_dw3b = (const float*)d_in[10];
    const float* b_dw3b = (const float*)d_in[11];
    const float* w_out  = (const float*)d_in[12];
    const float* b_out  = (const float*)d_in[13];
    float* outp = (float*)d_out;

    if (ws_size >= XC_BYTES) {
        u16* xc = (u16*)d_ws;
        dim3 g1(256, 4), b1(256);    // 4 tiles of 64 px per block
        k1_proj_mfma<<<g1, b1, 0, stream>>>(xin, pnin, w_in, b_in, w_pn, b_pn, xc);
        dim3 g2(16, 16, 4), b2(512);
        k2_spatial<<<g2, b2, 0, stream>>>(xc, w_dw1, b_dw1, w_dw3a, b_dw3a,
                                          w_dw3b, b_dw3b, w_out, b_out, outp);
    } else {
        dim3 grid(16, 16, 4), blk(256);
        ffd_fused<<<grid, blk, 0, stream>>>(xin, pnin, w_in, b_in, w_pn, b_pn,
                                            w_dw1, b_dw1, w_dw3a, b_dw3a,
                                            w_dw3b, b_dw3b, w_out, b_out, outp);
    }
}

// Round 12
// 462.765 us; speedup vs baseline: 1.1325x; 1.0021x over previous
//
#include <hip/hip_runtime.h>
#include <hip/hip_bf16.h>

// Two-phase FeedForward_denoise:
//   K1 (r5/r6, best measured ~174 us): MFMA split-bf16 GEMM, 4 pixel-tiles/
//       block, LDS double buffer, weights loaded once, deferred epilogue,
//       direct scattered 8B stores.
//   K2 (r12): r6 structure + LDS bank-conflict padding. s_xc and s_d3a tile
//       row strides padded 20/18 -> 22 u16 (u32 stride 11, odd -> banks
//       rotate 11/row; kills the old stride-200-u32 (%32=8) row aliasing in
//       the B-phase window reads). Pure layout change: LDS 75776->78848 B,
//       still 2 blocks/CU (157.7 KB < 160 KB). Everything else r6 verbatim.
// Fallback to the fully-fused kernel if ws_size < 201 MB.

#define T 16
#define R20 20
#define R18 18
#define XRS 22   // s_xc row stride (u16), 20 cols + 2 pad
#define DRS 22   // s_d3a row stride (u16), 18 cols + 4 pad
#define HW 65536
#define XC_BYTES ((size_t)4 * 16 * HW * 24 * 2)

typedef unsigned short u16;
typedef unsigned int u32;

typedef __attribute__((ext_vector_type(8))) short bf16x8;
typedef __attribute__((ext_vector_type(4))) float f32x4;
typedef __attribute__((ext_vector_type(2))) float f32x2;

__device__ __forceinline__ float bflo(u32 w) {
    union { u32 i; float f; } v; v.i = w << 16; return v.f;
}
__device__ __forceinline__ float bfhi(u32 w) {
    union { u32 i; float f; } v; v.i = w & 0xffff0000u; return v.f;
}
__device__ __forceinline__ float bf2f(u16 u) {
    union { u32 i; float f; } v; v.i = ((u32)u) << 16; return v.f;
}
__device__ __forceinline__ u16 f2bf(float f) {
    union { float f; u32 i; } v; v.f = f;
    u32 x = v.i;
    u32 r = (x + 0x7fffu + ((x >> 16) & 1u)) >> 16;
    return (u16)r;
}
__device__ __forceinline__ u32 f2bf2(float a, float b) {
    return (u32)f2bf(a) | ((u32)f2bf(b) << 16);
}
__device__ __forceinline__ float gelu_exact(float v) {
    return 0.5f * v * (1.0f + erff(v * 0.70710678118654752f));
}
// Branch-free erf, A&S 7.1.26 (|err| ~1e-6) — inputs bf16-rounded already.
__device__ __forceinline__ float erf_fast(float x) {
    float ax = fabsf(x);
    float t = __builtin_amdgcn_rcpf(fmaf(0.3275911f, ax, 1.0f));
    float p = fmaf(t, 1.061405429f, -1.453152027f);
    p = fmaf(t, p, 1.421413741f);
    p = fmaf(t, p, -0.284496736f);
    p = fmaf(t, p, 0.254829592f);
    p = p * t;
    float e = __expf(-ax * ax);
    float r = fmaf(-p, e, 1.0f);
    return copysignf(r, x);
}
__device__ __forceinline__ float gelu_fast(float v) {
    return 0.5f * v * (1.0f + erf_fast(v * 0.70710678118654752f));
}

// Exact split of two fp32 into packed-bf16 hi (truncated) and lo (residual).
__device__ __forceinline__ void pack_pair(float a, float b, u32& hi, u32& lo) {
    union { float f; u32 i; } ua, ub, ha, hb, la, lb;
    ua.f = a; ub.f = b;
    ha.i = ua.i & 0xffff0000u;
    hb.i = ub.i & 0xffff0000u;
    hi = (ha.i >> 16) | hb.i;
    la.f = a - ha.f;
    lb.f = b - hb.f;
    lo = (la.i >> 16) | (lb.i & 0xffff0000u);
}

// ---------------------------------------------------------------------------
// K1: MFMA split-bf16 GEMM, 4 tiles/block, LDS dbuf, direct global stores.
// (r6 verbatim)
// ---------------------------------------------------------------------------
__global__ __launch_bounds__(256, 2)
void k1_proj_mfma(const float* __restrict__ xin,   // [4][64][256][256]
                  const float* __restrict__ pnin,  // [4][2][256][256]
                  const float* __restrict__ w_in,  // [256][64]
                  const float* __restrict__ b_in,  // [256]
                  const float* __restrict__ w_pn,  // [128][2]
                  const float* __restrict__ b_pn,  // [128]
                  u16* __restrict__ xc)            // [4][16][HW][24] bf16
{
    __shared__ float s_x[2][64][65];               // 2 x 16.6 KB
    __shared__ float s_bin[256];

    const int tid  = threadIdx.x;
    const int b    = blockIdx.y;
    const int pxbase = blockIdx.x * 256;           // 4 tiles of 64 px
    const int lane = tid & 63;
    const int wid  = tid >> 6;
    const int lr   = lane & 15;        // MFMA row/col-in-16 index
    const int lh   = lane >> 4;        // MFMA k-group index
    const int CB   = wid * 64;         // this wave's channel base
    const int wu   = __builtin_amdgcn_readfirstlane(wid);

    s_bin[tid] = b_in[tid];

    // ---- w fragments: hi/lo bf16, loaded once per block -------------------
    bf16x8 whi[4][2], wlo[4][2];
#pragma unroll
    for (int ci = 0; ci < 4; ++ci)
#pragma unroll
        for (int ks = 0; ks < 2; ++ks) {
            const float* wp = w_in + (size_t)(CB + 16 * ci + lr) * 64
                            + 32 * ks + 8 * lh;
            float4 A0 = *(const float4*)wp;
            float4 A1 = *(const float4*)(wp + 4);
            union { u32 u[4]; bf16x8 v; } H, L;
            pack_pair(A0.x, A0.y, H.u[0], L.u[0]);
            pack_pair(A0.z, A0.w, H.u[1], L.u[1]);
            pack_pair(A1.x, A1.y, H.u[2], L.u[2]);
            pack_pair(A1.z, A1.w, H.u[3], L.u[3]);
            whi[ci][ks] = H.v; wlo[ci][ks] = L.v;
        }

    // ---- prologue: stage tile 0 -------------------------------------------
    {
        const float* xb = xin + (size_t)b * 64 * HW + pxbase;
#pragma unroll
        for (int i = 0; i < 4; ++i) {
            int idx = tid + 256 * i;
            int row = idx >> 4, seg = (idx & 15) * 4;
            float4 v = *(const float4*)(xb + (size_t)row * HW + seg);
            s_x[0][row][seg + 0] = v.x; s_x[0][row][seg + 1] = v.y;
            s_x[0][row][seg + 2] = v.z; s_x[0][row][seg + 3] = v.w;
        }
    }

    int cur = 0;
#pragma unroll 1
    for (int t = 0; t < 4; ++t) {
        const int px0 = pxbase + t * 64;

        // issue next-tile global loads (land after this tile's compute)
        float4 nx[4];
        if (t < 3) {
            const float* xb = xin + (size_t)b * 64 * HW + px0 + 64;
#pragma unroll
            for (int i = 0; i < 4; ++i) {
                int idx = tid + 256 * i;
                int row = idx >> 4, seg = (idx & 15) * 4;
                nx[i] = *(const float4*)(xb + (size_t)row * HW + seg);
            }
        }
        float p0 = pnin[(size_t)b * 2 * HW + px0 + lane];
        float p1 = pnin[(size_t)b * 2 * HW + HW + px0 + lane];

        __syncthreads();   // s_x[cur] fully staged (prologue or prev tail)

        // ---- pn projection: direct 8B stores ------------------------------
#pragma unroll
        for (int q = 0; q < 8; ++q) {
            int k = 32 * wu + 4 * q;           // wave-uniform quad base, <128
            int c = k / 12, l = k - 12 * c;    // l in {0,4,8}
            float v0 = fmaf(w_pn[2*k+0], p0, fmaf(w_pn[2*k+1], p1, b_pn[k+0]));
            float v1 = fmaf(w_pn[2*k+2], p0, fmaf(w_pn[2*k+3], p1, b_pn[k+1]));
            float v2 = fmaf(w_pn[2*k+4], p0, fmaf(w_pn[2*k+5], p1, b_pn[k+2]));
            float v3 = fmaf(w_pn[2*k+6], p0, fmaf(w_pn[2*k+7], p1, b_pn[k+3]));
            uint2 val;
            val.x = f2bf2(v0, v1);
            val.y = f2bf2(v2, v3);
            *(uint2*)(xc + ((size_t)(b * 16 + c) * HW + px0 + lane) * 24 + l) = val;
        }

        // ---- MFMA: acc[ci][pj] = W[64ch x 64k] * X[64k x 64px] ------------
        f32x4 acc[4][4];
#pragma unroll
        for (int ci = 0; ci < 4; ++ci)
#pragma unroll
            for (int pj = 0; pj < 4; ++pj)
                acc[ci][pj] = (f32x4){0.f, 0.f, 0.f, 0.f};

#pragma unroll
        for (int pj = 0; pj < 4; ++pj) {
            bf16x8 xh[2], xl[2];
#pragma unroll
            for (int ks = 0; ks < 2; ++ks) {
                const int rb = 32 * ks + 8 * lh;
                const int cb = 16 * pj + lr;
                float x0 = s_x[cur][rb + 0][cb], x1 = s_x[cur][rb + 1][cb];
                float x2 = s_x[cur][rb + 2][cb], x3 = s_x[cur][rb + 3][cb];
                float x4 = s_x[cur][rb + 4][cb], x5 = s_x[cur][rb + 5][cb];
                float x6 = s_x[cur][rb + 6][cb], x7 = s_x[cur][rb + 7][cb];
                union { u32 u[4]; bf16x8 v; } H, L;
                pack_pair(x0, x1, H.u[0], L.u[0]);
                pack_pair(x2, x3, H.u[1], L.u[1]);
                pack_pair(x4, x5, H.u[2], L.u[2]);
                pack_pair(x6, x7, H.u[3], L.u[3]);
                xh[ks] = H.v; xl[ks] = L.v;
            }
#pragma unroll
            for (int ci = 0; ci < 4; ++ci) {
#pragma unroll
                for (int ks = 0; ks < 2; ++ks) {
                    acc[ci][pj] = __builtin_amdgcn_mfma_f32_16x16x32_bf16(
                        whi[ci][ks], xh[ks], acc[ci][pj], 0, 0, 0);
                    acc[ci][pj] = __builtin_amdgcn_mfma_f32_16x16x32_bf16(
                        whi[ci][ks], xl[ks], acc[ci][pj], 0, 0, 0);
                    acc[ci][pj] = __builtin_amdgcn_mfma_f32_16x16x32_bf16(
                        wlo[ci][ks], xh[ks], acc[ci][pj], 0, 0, 0);
                }
            }
        }

        // ---- epilogue: bias + bf16 + direct stores ------------------------
#pragma unroll
        for (int ci = 0; ci < 4; ++ci) {
            const int kk = CB + 16 * ci + 4 * lh;
            float b0 = s_bin[kk + 0], b1 = s_bin[kk + 1];
            float b2 = s_bin[kk + 2], b3 = s_bin[kk + 3];
            int c, l;
            int kg = kk + 128;
            if (kg < 192) { c = kg / 12; l = kg - 12 * c; }
            else { int t2 = kg - 192; int cq = t2 / 12; c = cq; l = 12 + (t2 - 12 * cq); }
            u16* rec = xc + ((size_t)(b * 16 + c) * HW + px0) * 24 + l;
#pragma unroll
            for (int pj = 0; pj < 4; ++pj) {
                f32x4 a = acc[ci][pj];
                uint2 val;
                val.x = f2bf2(a[0] + b0, a[1] + b1);
                val.y = f2bf2(a[2] + b2, a[3] + b3);
                *(uint2*)(rec + (size_t)(16 * pj + lr) * 24) = val;
            }
        }

        // ---- tail: write prefetched tile into other buffer ----------------
        if (t < 3) {
#pragma unroll
            for (int i = 0; i < 4; ++i) {
                int idx = tid + 256 * i;
                int row = idx >> 4, seg = (idx & 15) * 4;
                float* d = &s_x[cur ^ 1][row][seg];
                d[0] = nx[i].x; d[1] = nx[i].y; d[2] = nx[i].z; d[3] = nx[i].w;
            }
            cur ^= 1;
        }
    }
}

// ---------------------------------------------------------------------------
// K2: spatial convs + gating; project_out via MFMA gate passes.
// r12: padded tile row strides (XRS/DRS = 22) for bank-conflict-free reads.
// ---------------------------------------------------------------------------
__global__ __launch_bounds__(512, 2)
void k2_spatial(const u16* __restrict__ xc,       // [4][16][HW][24] bf16
                const float* __restrict__ w_dw1,  const float* __restrict__ b_dw1,
                const float* __restrict__ w_dw3a, const float* __restrict__ b_dw3a,
                const float* __restrict__ w_dw3b, const float* __restrict__ b_dw3b,
                const float* __restrict__ w_out,  const float* __restrict__ b_out,
                float* __restrict__ outp)         // [4][64][256][256]
{
    __shared__ __align__(8) u16 s_xc[24][20 * XRS];   // 20 rows, stride 22
    __shared__ __align__(8) u16 s_d3a[8][18 * DRS];   // 18 rows, stride 22
    __shared__ __align__(8) u16 s_d1[8][T * T];
    __shared__ __align__(8) u16 s_d3[8][T * T];
    __shared__ __align__(16) u16 s_g[2][256][40];  // [half][px][gate-col ring]
    __shared__ float s_wd1[8][27];
    __shared__ float s_wd3a[8][27];
    __shared__ float s_wd3b[8][9];
    __shared__ float s_b1[8], s_b3a[8], s_b3b[8];

    const int tid  = threadIdx.x;
    const int half = tid >> 8;          // wave-uniform (waves 0-3 vs 4-7)
    const int pix  = tid & 255;
    const int ox0 = blockIdx.x * T;
    const int oy0 = blockIdx.y * T;
    const int b   = blockIdx.z;

    // MFMA pass role: wave w -> gh (which gate half), cw (ch-tile),
    // ph (px-half). Out rows [32gh+16cw, +16), px-tiles 8ph..8ph+7.
    const int w    = tid >> 6;
    const int lane = tid & 63;
    const int lr   = lane & 15;
    const int lh   = lane >> 4;
    const int gh   = w >> 2;
    const int cw   = (w >> 1) & 1;
    const int ph   = w & 1;

    // ---- halo prefetch state (chunk-invariant coords) ---------------------
    int hpy = tid / R20, hpx = tid - hpy * R20;     // meaningful for tid<400
    int hgy = oy0 - 2 + hpy, hgx = ox0 - 2 + hpx;
    const bool pvalid = (tid < 400) &&
                        ((unsigned)hgy < 256u) && ((unsigned)hgx < 256u);
    const u16* psrc = xc + ((size_t)(b * 16) * HW
                            + (pvalid ? (hgy * 256 + hgx) : 0)) * 24;
    uint4 pv0, pv1, pv2;
    pv0 = pv1 = pv2 = make_uint4(0, 0, 0, 0);
    if (pvalid) {
        const uint4* s = (const uint4*)psrc;
        pv0 = s[0]; pv1 = s[1]; pv2 = s[2];
    }

    f32x4 acc[8];      // 8 px-tiles of this wave's 16-ch out slice
#pragma unroll
    for (int t = 0; t < 8; ++t) acc[t] = (f32x4){0.f, 0.f, 0.f, 0.f};

    for (int chunk = 0; chunk < 16; ++chunk) {
        const int c0 = chunk * 4;
        __syncthreads();   // protect s_* reuse across chunks

        // ---- Phase W: stage chunk weights into LDS -------------------------
        {
            int t = tid;
            if (t < 216) {
                int gl = t / 27, idx = t - gl * 27;
                int g = (gl < 4) ? (c0 + gl) : (c0 + 60 + gl);
                s_wd1[gl][idx] = w_dw1[g * 27 + idx];
            } else if (t < 432) {
                int t2 = t - 216;
                int gl = t2 / 27, idx = t2 - gl * 27;
                int g = (gl < 4) ? (c0 + gl) : (c0 + 60 + gl);
                s_wd3a[gl][idx] = w_dw3a[g * 27 + idx];
            } else if (t < 504) {
                int t2 = t - 432;
                int gl = t2 / 9, idx = t2 - gl * 9;
                int g = (gl < 4) ? (c0 + gl) : (c0 + 60 + gl);
                s_wd3b[gl][idx] = w_dw3b[g * 9 + idx];
            } else if (t < 512) {
                int gl = t - 504;
                int g = (gl < 4) ? (c0 + gl) : (c0 + 60 + gl);
                s_b1[gl]  = b_dw1[g];
                s_b3a[gl] = b_dw3a[g];
                s_b3b[gl] = b_dw3b[g];
            }
        }

        // ---- Phase A: write prefetched halo (padded rows), issue chunk+1 --
        if (tid < 400) {
            union { uint4 q[3]; u16 h[24]; } v;
            v.q[0] = pv0; v.q[1] = pv1; v.q[2] = pv2;
            const int hidx = hpy * XRS + hpx;
#pragma unroll
            for (int l = 0; l < 24; ++l) s_xc[l][hidx] = v.h[l];
        }
        {
            uint4 n0, n1, n2;
            n0 = n1 = n2 = make_uint4(0, 0, 0, 0);
            if (pvalid && chunk < 15) {
                const uint4* s = (const uint4*)(psrc
                                 + (size_t)(chunk + 1) * HW * 24);
                n0 = s[0]; n1 = s[1]; n2 = s[2];
            }
            pv0 = n0; pv1 = n1; pv2 = n2;   // waitcnt lands at next-iter use
        }
        __syncthreads();

        // ---- Phase B1a: d3a (grouped 3x3) over 18x18, 2x2 per thread -------
        for (int task = tid; task < 8 * 81; task += 512) {
            int gl = task / 81, patch = task - gl * 81;
            int py = (patch / 9) * 2, px = (patch - (patch / 9) * 9) * 2;
            float bias = s_b3a[gl];
            float a00 = bias, a01 = bias, a10 = bias, a11 = bias;
#pragma unroll
            for (int j = 0; j < 3; ++j) {
                int lc = (gl < 4) ? (3 * gl + j) : (12 + 3 * (gl - 4) + j);
                const u32* base = (const u32*)&s_xc[lc][0];
                float win[4][4];
#pragma unroll
                for (int r = 0; r < 4; ++r) {
                    int e = (py + r) * XRS + px;   // even (XRS even, px even)
                    u32 u0 = base[e >> 1];
                    u32 u1 = base[(e >> 1) + 1];
                    win[r][0] = bflo(u0); win[r][1] = bfhi(u0);
                    win[r][2] = bflo(u1); win[r][3] = bfhi(u1);
                }
#pragma unroll
                for (int ky = 0; ky < 3; ++ky)
#pragma unroll
                    for (int kx = 0; kx < 3; ++kx) {
                        float wgt = s_wd3a[gl][j * 9 + ky * 3 + kx];
                        a00 = fmaf(wgt, win[ky][kx], a00);
                        a01 = fmaf(wgt, win[ky][kx + 1], a01);
                        a10 = fmaf(wgt, win[ky + 1][kx], a10);
                        a11 = fmaf(wgt, win[ky + 1][kx + 1], a11);
                    }
            }
            int gy0 = oy0 - 1 + py, gx0 = ox0 - 1 + px;
            bool vy0 = (unsigned)gy0 < 256u, vy1 = (unsigned)(gy0 + 1) < 256u;
            bool vx0 = (unsigned)gx0 < 256u, vx1 = (unsigned)(gx0 + 1) < 256u;
            u16* drow = &s_d3a[gl][py * DRS + px];
            drow[0]       = (vy0 && vx0) ? f2bf(a00) : (u16)0;
            drow[1]       = (vy0 && vx1) ? f2bf(a01) : (u16)0;
            drow[DRS]     = (vy1 && vx0) ? f2bf(a10) : (u16)0;
            drow[DRS + 1] = (vy1 && vx1) ? f2bf(a11) : (u16)0;
        }

        // ---- Phase B1b: d1 (grouped 3x3), one 2x2 task per thread ----------
        {
            int gl = tid >> 6, patch = tid & 63;
            int py = (patch >> 3) * 2, px = (patch & 7) * 2;
            float bias = s_b1[gl];
            float a00 = bias, a01 = bias, a10 = bias, a11 = bias;
#pragma unroll
            for (int j = 0; j < 3; ++j) {
                int lc = (gl < 4) ? (3 * gl + j) : (12 + 3 * (gl - 4) + j);
                const u32* base = (const u32*)&s_xc[lc][0];
                float win[4][4];
#pragma unroll
                for (int r = 0; r < 4; ++r) {
                    int e = (py + 1 + r) * XRS + px;   // even; cols px+1..px+4
                    u32 u0 = base[e >> 1];
                    u32 u1 = base[(e >> 1) + 1];
                    u32 u2 = base[(e >> 1) + 2];
                    win[r][0] = bfhi(u0); win[r][1] = bflo(u1);
                    win[r][2] = bfhi(u1); win[r][3] = bflo(u2);
                }
#pragma unroll
                for (int ky = 0; ky < 3; ++ky)
#pragma unroll
                    for (int kx = 0; kx < 3; ++kx) {
                        float wgt = s_wd1[gl][j * 9 + ky * 3 + kx];
                        a00 = fmaf(wgt, win[ky][kx], a00);
                        a01 = fmaf(wgt, win[ky][kx + 1], a01);
                        a10 = fmaf(wgt, win[ky + 1][kx], a10);
                        a11 = fmaf(wgt, win[ky + 1][kx + 1], a11);
                    }
            }
            u16* drow = &s_d1[gl][py * T + px];
            drow[0] = f2bf(a00); drow[1] = f2bf(a01);
            drow[T] = f2bf(a10); drow[T + 1] = f2bf(a11);
        }
        __syncthreads();

        // ---- Phase B2: d3 = depthwise 3x3 over d3a, one task per thread ----
        {
            int gl = tid >> 6, patch = tid & 63;
            int py = (patch >> 3) * 2, px = (patch & 7) * 2;
            float bias = s_b3b[gl];
            float a00 = bias, a01 = bias, a10 = bias, a11 = bias;
            float win[4][4];
            const u32* base = (const u32*)&s_d3a[gl][0];
#pragma unroll
            for (int r = 0; r < 4; ++r) {
                int e = (py + r) * DRS + px;   // even
                u32 u0 = base[e >> 1];
                u32 u1 = base[(e >> 1) + 1];
                win[r][0] = bflo(u0); win[r][1] = bfhi(u0);
                win[r][2] = bflo(u1); win[r][3] = bfhi(u1);
            }
#pragma unroll
            for (int ky = 0; ky < 3; ++ky)
#pragma unroll
                for (int kx = 0; kx < 3; ++kx) {
                    float wgt = s_wd3b[gl][ky * 3 + kx];
                    a00 = fmaf(wgt, win[ky][kx], a00);
                    a01 = fmaf(wgt, win[ky][kx + 1], a01);
                    a10 = fmaf(wgt, win[ky + 1][kx], a10);
                    a11 = fmaf(wgt, win[ky + 1][kx + 1], a11);
                }
            u16* drow = &s_d3[gl][py * T + px];
            drow[0] = f2bf(a00); drow[1] = f2bf(a01);
            drow[T] = f2bf(a10); drow[T + 1] = f2bf(a11);
        }
        __syncthreads();

        // ---- Phase G: gate products -> s_g (bf16), one 8B write -----------
        {
            const u16* sD = (half == 0) ? &s_d1[0][0] : &s_d3[0][0];
            float ga = gelu_fast(bf2f(sD[0 * 256 + pix])) * bf2f(sD[4 * 256 + pix]);
            float gb = gelu_fast(bf2f(sD[1 * 256 + pix])) * bf2f(sD[5 * 256 + pix]);
            float gc = gelu_fast(bf2f(sD[2 * 256 + pix])) * bf2f(sD[6 * 256 + pix]);
            float gd = gelu_fast(bf2f(sD[3 * 256 + pix])) * bf2f(sD[7 * 256 + pix]);
            uint2 val;
            val.x = f2bf2(ga, gb);
            val.y = f2bf2(gc, gd);
            *(uint2*)&s_g[half][pix][c0 & 31] = val;
        }

        // ---- MFMA pass after chunks 7 and 15 (gate cols 0..31 / 32..63) ---
        if (chunk == 7 || chunk == 15) {
            __syncthreads();   // s_g complete for this 32-col window
            const int p = chunk >> 3;
            // A-frag: w_out rows [32gh+16cw+lr], cols 32p+8lh .. +7 (split)
            const float* wp = w_out + (size_t)(32 * gh + 16 * cw + lr) * 64
                            + 32 * p + 8 * lh;
            float4 A0 = *(const float4*)wp;
            float4 A1 = *(const float4*)(wp + 4);
            union { u32 u[4]; bf16x8 v; } H, L;
            pack_pair(A0.x, A0.y, H.u[0], L.u[0]);
            pack_pair(A0.z, A0.w, H.u[1], L.u[1]);
            pack_pair(A1.x, A1.y, H.u[2], L.u[2]);
            pack_pair(A1.z, A1.w, H.u[3], L.u[3]);
            bf16x8 Ah = H.v, Al = L.v;
#pragma unroll
            for (int t = 0; t < 8; ++t) {
                int pt = 8 * ph + t;
                bf16x8 Bv = *(const bf16x8*)&s_g[gh][16 * pt + lr][8 * lh];
                acc[t] = __builtin_amdgcn_mfma_f32_16x16x32_bf16(Ah, Bv, acc[t], 0, 0, 0);
                acc[t] = __builtin_amdgcn_mfma_f32_16x16x32_bf16(Al, Bv, acc[t], 0, 0, 0);
            }
        }
    }

    // ---- Epilogue: bias + fp32 store --------------------------------------
    // D-frag: value r of px-tile t is out[o = 32gh+16cw+4lh+r][px = 16pt+lr]
    {
        const int o = 32 * gh + 16 * cw + 4 * lh;
        float b0 = b_out[o + 0], b1 = b_out[o + 1];
        float b2 = b_out[o + 2], b3 = b_out[o + 3];
#pragma unroll
        for (int t = 0; t < 8; ++t) {
            int pt = 8 * ph + t;
            size_t base = (size_t)b * 64 * HW + (size_t)o * HW
                        + (size_t)(oy0 + pt) * 256 + (ox0 + lr);
            outp[base + 0 * HW] = acc[t][0] + b0;
            outp[base + 1 * HW] = acc[t][1] + b1;
            outp[base + 2 * HW] = acc[t][2] + b2;
            outp[base + 3 * HW] = acc[t][3] + b3;
        }
    }
}

// ---------------------------------------------------------------------------
// Fallback: fully-fused kernel (used only if ws_size < 201 MB).
// ---------------------------------------------------------------------------
__global__ __launch_bounds__(256, 2)
void ffd_fused(const float* __restrict__ xin, const float* __restrict__ pnin,
               const float* __restrict__ w_in, const float* __restrict__ b_in,
               const float* __restrict__ w_pn, const float* __restrict__ b_pn,
               const float* __restrict__ w_dw1, const float* __restrict__ b_dw1,
               const float* __restrict__ w_dw3a, const float* __restrict__ b_dw3a,
               const float* __restrict__ w_dw3b, const float* __restrict__ b_dw3b,
               const float* __restrict__ w_out, const float* __restrict__ b_out,
               float* __restrict__ outp)
{
    __shared__ __align__(8) u16 s_xc[24][R20 * R20];
    __shared__ __align__(8) float s_d3a[8][R18 * R18];
    __shared__ float s_d1[8][T * T];
    __shared__ float s_d3[8][T * T];
    __shared__ float s_wd1[8][27];
    __shared__ float s_wd3a[8][27];
    __shared__ float s_wd3b[8][9];
    __shared__ float s_b1[8], s_b3a[8], s_b3b[8];

    const int tid = threadIdx.x;
    const int ox0 = blockIdx.x * T;
    const int oy0 = blockIdx.y * T;
    const int b   = blockIdx.z;

    float accL[32], accH[32];
#pragma unroll
    for (int o = 0; o < 32; ++o) { accL[o] = 0.f; accH[o] = 0.f; }

    for (int chunk = 0; chunk < 16; ++chunk) {
        const int c0 = chunk * 4;
        __syncthreads();

        for (int t = tid; t < 512; t += 256) {
            if (t < 216) {
                int gl = t / 27, idx = t - gl * 27;
                int g = (gl < 4) ? (c0 + gl) : (c0 + 60 + gl);
                s_wd1[gl][idx] = w_dw1[g * 27 + idx];
            } else if (t < 432) {
                int t2 = t - 216;
                int gl = t2 / 27, idx = t2 - gl * 27;
                int g = (gl < 4) ? (c0 + gl) : (c0 + 60 + gl);
                s_wd3a[gl][idx] = w_dw3a[g * 27 + idx];
            } else if (t < 504) {
                int t2 = t - 432;
                int gl = t2 / 9, idx = t2 - gl * 9;
                int g = (gl < 4) ? (c0 + gl) : (c0 + 60 + gl);
                s_wd3b[gl][idx] = w_dw3b[g * 9 + idx];
            } else {
                int gl = t - 504;
                int g = (gl < 4) ? (c0 + gl) : (c0 + 60 + gl);
                s_b1[gl]  = b_dw1[g];
                s_b3a[gl] = b_dw3a[g];
                s_b3b[gl] = b_dw3b[g];
            }
        }

        for (int p = tid; p < R20 * R20; p += 256) {
            int py = p / R20, px = p - py * R20;
            int gy = oy0 - 2 + py, gx = ox0 - 2 + px;
            if ((unsigned)gy >= 256u || (unsigned)gx >= 256u) {
#pragma unroll 1
                for (int l = 0; l < 24; ++l) s_xc[l][p] = 0;
                continue;
            }
            const int off = gy * 256 + gx;
            float xr[64];
            const float* xp = xin + (size_t)b * 64 * HW + off;
#pragma unroll
            for (int c = 0; c < 64; ++c) xr[c] = xp[(size_t)c * HW];
            float p0 = 0.f, p1 = 0.f;
            if (3 * c0 < 128) {
                const float* pp = pnin + (size_t)b * 2 * HW + off;
                p0 = pp[0]; p1 = pp[HW];
            }
#pragma unroll 1
            for (int l = 0; l < 24; ++l) {
                int k = (l < 12) ? (3 * c0 + l) : (3 * c0 + 192 + (l - 12));
                float acc;
                if (k < 128) {
                    acc = b_pn[k] + w_pn[2 * k] * p0 + w_pn[2 * k + 1] * p1;
                } else {
                    int kk = k - 128;
                    acc = b_in[kk];
                    const float2* wr = (const float2*)(w_in + kk * 64);
#pragma unroll
                    for (int i = 0; i < 32; ++i) {
                        float2 w2 = wr[i];
                        acc = fmaf(w2.x, xr[2 * i], acc);
                        acc = fmaf(w2.y, xr[2 * i + 1], acc);
                    }
                }
                s_xc[l][p] = f2bf(acc);
            }
        }
        __syncthreads();

        for (int task = tid; task < 8 * 81; task += 256) {
            int gl = task / 81, patch = task - gl * 81;
            int py = (patch / 9) * 2, px = (patch - (patch / 9) * 9) * 2;
            float bias = s_b3a[gl];
            float a00 = bias, a01 = bias, a10 = bias, a11 = bias;
#pragma unroll
            for (int j = 0; j < 3; ++j) {
                int lc = (gl < 4) ? (3 * gl + j) : (12 + 3 * (gl - 4) + j);
                const u32* base = (const u32*)&s_xc[lc][0];
                float win[4][4];
#pragma unroll
                for (int r = 0; r < 4; ++r) {
                    int e = (py + r) * R20 + px;
                    u32 u0 = base[e >> 1];
                    u32 u1 = base[(e >> 1) + 1];
                    win[r][0] = bflo(u0); win[r][1] = bfhi(u0);
                    win[r][2] = bflo(u1); win[r][3] = bfhi(u1);
                }
#pragma unroll
                for (int ky = 0; ky < 3; ++ky)
#pragma unroll
                    for (int kx = 0; kx < 3; ++kx) {
                        float wgt = s_wd3a[gl][j * 9 + ky * 3 + kx];
                        a00 = fmaf(wgt, win[ky][kx], a00);
                        a01 = fmaf(wgt, win[ky][kx + 1], a01);
                        a10 = fmaf(wgt, win[ky + 1][kx], a10);
                        a11 = fmaf(wgt, win[ky + 1][kx + 1], a11);
                    }
            }
            int gy0 = oy0 - 1 + py, gx0 = ox0 - 1 + px;
            bool vy0 = (unsigned)gy0 < 256u, vy1 = (unsigned)(gy0 + 1) < 256u;
            bool vx0 = (unsigned)gx0 < 256u, vx1 = (unsigned)(gx0 + 1) < 256u;
            float* drow = &s_d3a[gl][py * R18 + px];
            drow[0]       = (vy0 && vx0) ? a00 : 0.f;
            drow[1]       = (vy0 && vx1) ? a01 : 0.f;
            drow[R18]     = (vy1 && vx0) ? a10 : 0.f;
            drow[R18 + 1] = (vy1 && vx1) ? a11 : 0.f;
        }

        for (int task = tid; task < 8 * 64; task += 256) {
            int gl = task >> 6, patch = task & 63;
            int py = (patch >> 3) * 2, px = (patch & 7) * 2;
            float bias = s_b1[gl];
            float a00 = bias, a01 = bias, a10 = bias, a11 = bias;
#pragma unroll
            for (int j = 0; j < 3; ++j) {
                int lc = (gl < 4) ? (3 * gl + j) : (12 + 3 * (gl - 4) + j);
                const u32* base = (const u32*)&s_xc[lc][0];
                float win[4][4];
#pragma unroll
                for (int r = 0; r < 4; ++r) {
                    int e = (py + 1 + r) * R20 + px;
                    u32 u0 = base[e >> 1];
                    u32 u1 = base[(e >> 1) + 1];
                    u32 u2 = base[(e >> 1) + 2];
                    win[r][0] = bfhi(u0); win[r][1] = bflo(u1);
                    win[r][2] = bfhi(u1); win[r][3] = bflo(u2);
                }
#pragma unroll
                for (int ky = 0; ky < 3; ++ky)
#pragma unroll
                    for (int kx = 0; kx < 3; ++kx) {
                        float wgt = s_wd1[gl][j * 9 + ky * 3 + kx];
                        a00 = fmaf(wgt, win[ky][kx], a00);
                        a01 = fmaf(wgt, win[ky][kx + 1], a01);
                        a10 = fmaf(wgt, win[ky + 1][kx], a10);
                        a11 = fmaf(wgt, win[ky + 1][kx + 1], a11);
                    }
            }
            float* drow = &s_d1[gl][py * T + px];
            drow[0] = a00; drow[1] = a01; drow[T] = a10; drow[T + 1] = a11;
        }
        __syncthreads();

        for (int task = tid; task < 8 * 64; task += 256) {
            int gl = task >> 6, patch = task & 63;
            int py = (patch >> 3) * 2, px = (patch & 7) * 2;
            float bias = s_b3b[gl];
            float a00 = bias, a01 = bias, a10 = bias, a11 = bias;
            float win[4][4];
#pragma unroll
            for (int r = 0; r < 4; ++r) {
                int e = (py + r) * R18 + px;
                float2 f0 = *(const float2*)&s_d3a[gl][e];
                float2 f1 = *(const float2*)&s_d3a[gl][e + 2];
                win[r][0] = f0.x; win[r][1] = f0.y;
                win[r][2] = f1.x; win[r][3] = f1.y;
            }
#pragma unroll
            for (int ky = 0; ky < 3; ++ky)
#pragma unroll
                for (int kx = 0; kx < 3; ++kx) {
                    float wgt = s_wd3b[gl][ky * 3 + kx];
                    a00 = fmaf(wgt, win[ky][kx], a00);
                    a01 = fmaf(wgt, win[ky][kx + 1], a01);
                    a10 = fmaf(wgt, win[ky + 1][kx], a10);
                    a11 = fmaf(wgt, win[ky + 1][kx + 1], a11);
                }
            float* drow = &s_d3[gl][py * T + px];
            drow[0] = a00; drow[1] = a01; drow[T] = a10; drow[T + 1] = a11;
        }
        __syncthreads();

#pragma unroll
        for (int jp = 0; jp < 2; ++jp) {
            int j0 = 2 * jp;
            float g1a = gelu_exact(s_d1[j0][tid])     * s_d1[j0 + 4][tid];
            float g1b = gelu_exact(s_d1[j0 + 1][tid]) * s_d1[j0 + 5][tid];
            float g2a = gelu_exact(s_d3[j0][tid])     * s_d3[j0 + 4][tid];
            float g2b = gelu_exact(s_d3[j0 + 1][tid]) * s_d3[j0 + 5][tid];
            int c = c0 + j0;
#pragma unroll
            for (int o = 0; o < 32; ++o) {
                float2 wL = *(const float2*)(w_out + o * 64 + c);
                accL[o] = fmaf(wL.x, g1a, accL[o]);
                accL[o] = fmaf(wL.y, g1b, accL[o]);
                float2 wH = *(const float2*)(w_out + (o + 32) * 64 + c);
                accH[o] = fmaf(wH.x, g2a, accH[o]);
                accH[o] = fmaf(wH.y, g2b, accH[o]);
            }
        }
    }

    {
        int py = tid >> 4, pxx = tid & 15;
        size_t obase = (size_t)b * 64 * HW
                     + (size_t)(oy0 + py) * 256 + (ox0 + pxx);
#pragma unroll
        for (int o = 0; o < 32; ++o) {
            outp[obase + (size_t)o * HW]        = accL[o] + b_out[o];
            outp[obase + (size_t)(o + 32) * HW] = accH[o] + b_out[o + 32];
        }
    }
}

extern "C" void kernel_launch(void* const* d_in, const int* in_sizes, int n_in,
                              void* d_out, int out_size, void* d_ws, size_t ws_size,
                              hipStream_t stream) {
    (void)in_sizes; (void)n_in; (void)out_size;
    const float* xin    = (const float*)d_in[0];
    const float* pnin   = (const float*)d_in[1];
    const float* w_in   = (const float*)d_in[2];
    const float* b_in   = (const float*)d_in[3];
    const float* w_pn   = (const float*)d_in[4];
    const float* b_pn   = (const float*)d_in[5];
    const float* w_dw1  = (const float*)d_in[6];
    const float* b_dw1  = (const float*)d_in[7];
    const float* w_dw3a = (const float*)d_in[8];
    const float* b_dw3a = (const float*)d_in[9];
    const float* w_dw3b = (const float*)d_in[10];
    const float* b_dw3b = (const float*)d_in[11];
    const float* w_out  = (const float*)d_in[12];
    const float* b_out  = (const float*)d_in[13];
    float* outp = (float*)d_out;

    if (ws_size >= XC_BYTES) {
        u16* xc = (u16*)d_ws;
        dim3 g1(256, 4), b1(256);    // 4 tiles of 64 px per block
        k1_proj_mfma<<<g1, b1, 0, stream>>>(xin, pnin, w_in, b_in, w_pn, b_pn, xc);
        dim3 g2(16, 16, 4), b2(512);
        k2_spatial<<<g2, b2, 0, stream>>>(xc, w_dw1, b_dw1, w_dw3a, b_dw3a,
                                          w_dw3b, b_dw3b, w_out, b_out, outp);
    } else {
        dim3 grid(16, 16, 4), blk(256);
        ffd_fused<<<grid, blk, 0, stream>>>(xin, pnin, w_in, b_in, w_pn, b_pn,
                                            w_dw1, b_dw1, w_dw3a, b_dw3a,
                                            w_dw3b, b_dw3b, w_out, b_out, outp);
    }
}